// Round 1
// baseline (762.888 us; speedup 1.0000x reference)
//
#include <hip/hip_runtime.h>
#include <hip/hip_bf16.h>
#include <stdint.h>

#define T_TOK 8192
#define H_DIM 2048
#define I_DIM 1408
#define E_NUM 8
#define GU2   2816   // 2*I

typedef __attribute__((ext_vector_type(8))) short bf16x8;
typedef __attribute__((ext_vector_type(4))) float f32x4;

__device__ __forceinline__ void async_copy16(void* lds, const void* g) {
  __builtin_amdgcn_global_load_lds(
      (const __attribute__((address_space(1))) uint32_t*)g,
      (__attribute__((address_space(3))) uint32_t*)lds, 16, 0, 0);
}

// ---------------- f32 -> bf16 conversion (vectorized) ----------------
__global__ __launch_bounds__(256) void cvt_kernel(const float4* __restrict__ in,
                                                  ushort4* __restrict__ out, int n4) {
  int i = blockIdx.x * blockDim.x + threadIdx.x;
  int stride = gridDim.x * blockDim.x;
  for (; i < n4; i += stride) {
    float4 v = in[i];
    ushort4 o;
    __hip_bfloat16 b;
    b = __float2bfloat16(v.x); o.x = *reinterpret_cast<unsigned short*>(&b);
    b = __float2bfloat16(v.y); o.y = *reinterpret_cast<unsigned short*>(&b);
    b = __float2bfloat16(v.z); o.z = *reinterpret_cast<unsigned short*>(&b);
    b = __float2bfloat16(v.w); o.w = *reinterpret_cast<unsigned short*>(&b);
    out[i] = o;
  }
}

// ---------------- gating: logits -> softmax -> top2 -> lists ----------------
__global__ __launch_bounds__(256) void gating_kernel(
    const float* __restrict__ x, const float* __restrict__ gw,
    int* __restrict__ cnt, int* __restrict__ idx, float* __restrict__ wgt) {
  int wave = threadIdx.x >> 6, lane = threadIdx.x & 63;
  int t = blockIdx.x * 4 + wave;
  if (t >= T_TOK) return;
  const float* xr = x + (size_t)t * H_DIM;
  float acc[E_NUM];
#pragma unroll
  for (int e = 0; e < E_NUM; ++e) acc[e] = 0.f;
  for (int k = lane; k < H_DIM; k += 64) {
    float xv = xr[k];
#pragma unroll
    for (int e = 0; e < E_NUM; ++e) acc[e] += xv * gw[e * H_DIM + k];
  }
#pragma unroll
  for (int e = 0; e < E_NUM; ++e) {
    float s = acc[e];
#pragma unroll
    for (int o = 32; o > 0; o >>= 1) s += __shfl_xor(s, o);
    acc[e] = s;
  }
  if (lane == 0) {
    int i1 = 0; float v1 = acc[0];
#pragma unroll
    for (int e = 1; e < E_NUM; ++e) if (acc[e] > v1) { v1 = acc[e]; i1 = e; }
    int i2 = -1; float v2 = -3.4e38f;
#pragma unroll
    for (int e = 0; e < E_NUM; ++e) if (e != i1 && acc[e] > v2) { v2 = acc[e]; i2 = e; }
    // softmax-then-renormalize over top2 == pairwise softmax of (v1, v2)
    float p2 = expf(v2 - v1);
    float winv = 1.f / (1.f + p2);
    float w1 = winv, w2 = p2 * winv;
    int p = atomicAdd(&cnt[i1], 1);
    idx[i1 * T_TOK + p] = t; wgt[i1 * T_TOK + p] = w1;
    p = atomicAdd(&cnt[i2], 1);
    idx[i2 * T_TOK + p] = t; wgt[i2 * T_TOK + p] = w2;
  }
}

__global__ void prefix_kernel(const int* __restrict__ cnt, int* __restrict__ base) {
  if (threadIdx.x == 0 && blockIdx.x == 0) {
    int s = 0;
#pragma unroll
    for (int e = 0; e < E_NUM; ++e) { base[e] = s; s += cnt[e]; }
  }
}

// ---------------- GEMM1: h = silu(x@Wg^T) * (x@Wu^T), gathered rows ----------------
// Block: 128 rows x 64 h-cols (dual 64-wide g and u output tiles). 4 waves (2x2).
__global__ __launch_bounds__(256, 2) void gemm1_kernel(
    const __hip_bfloat16* __restrict__ xb,   // [T][H] bf16
    const __hip_bfloat16* __restrict__ wb1,  // [E][GU2][H] bf16
    const int* __restrict__ cnt, const int* __restrict__ base,
    const int* __restrict__ idx,
    __hip_bfloat16* __restrict__ hbuf)       // [16384][I] bf16, compact per expert
{
  const int e = blockIdx.z;
  const int ne = cnt[e];
  const int rowbase = blockIdx.y * 128;
  if (rowbase >= ne) return;
  const int jbase = blockIdx.x * 64;
  const int hb = base[e];

  __shared__ short sA[128][64];
  __shared__ short sBg[64][64];
  __shared__ short sBu[64][64];

  const int tid = threadIdx.x, wid = tid >> 6, lane = tid & 63;
  const int* idx_e = idx + e * T_TOK;
  const short* xs = (const short*)xb;
  const short* w1s = (const short*)wb1 + (size_t)e * GU2 * H_DIM;

  // Precompute per-lane global source addresses (row fixed across K-steps)
  const short* aSrc[4];
#pragma unroll
  for (int it = 0; it < 4; ++it) {
    int ci = it * 4 + wid;
    int off = ci * 512 + lane * 8;
    int row = off >> 6, col = off & 63;
    int i = rowbase + row; if (i > ne - 1) i = ne - 1;
    int tok = idx_e[i];
    aSrc[it] = xs + (size_t)tok * H_DIM + col;
  }
  const short* bgSrc[2]; const short* buSrc[2];
#pragma unroll
  for (int it = 0; it < 2; ++it) {
    int ci = it * 4 + wid;
    int off = ci * 512 + lane * 8;
    int row = off >> 6, col = off & 63;
    bgSrc[it] = w1s + (size_t)(jbase + row) * H_DIM + col;
    buSrc[it] = w1s + (size_t)(I_DIM + jbase + row) * H_DIM + col;
  }

  const int wr = wid >> 1, wc = wid & 1;
  f32x4 accg[4][2], accu[4][2];
#pragma unroll
  for (int m = 0; m < 4; ++m)
#pragma unroll
    for (int n = 0; n < 2; ++n) { accg[m][n] = (f32x4){0,0,0,0}; accu[m][n] = (f32x4){0,0,0,0}; }

  for (int k0 = 0; k0 < H_DIM; k0 += 64) {
#pragma unroll
    for (int it = 0; it < 4; ++it) {
      int ci = it * 4 + wid;
      async_copy16((short*)sA + ci * 512, aSrc[it] + k0);
    }
#pragma unroll
    for (int it = 0; it < 2; ++it) {
      int ci = it * 4 + wid;
      async_copy16((short*)sBg + ci * 512, bgSrc[it] + k0);
      async_copy16((short*)sBu + ci * 512, buSrc[it] + k0);
    }
    __syncthreads();
#pragma unroll
    for (int ks = 0; ks < 2; ++ks) {
      bf16x8 a[4], bg[2], bu[2];
#pragma unroll
      for (int m = 0; m < 4; ++m)
        a[m] = *(const bf16x8*)&sA[wr * 64 + m * 16 + (lane & 15)][ks * 32 + ((lane >> 4) << 3)];
#pragma unroll
      for (int n = 0; n < 2; ++n) {
        bg[n] = *(const bf16x8*)&sBg[wc * 32 + n * 16 + (lane & 15)][ks * 32 + ((lane >> 4) << 3)];
        bu[n] = *(const bf16x8*)&sBu[wc * 32 + n * 16 + (lane & 15)][ks * 32 + ((lane >> 4) << 3)];
      }
#pragma unroll
      for (int m = 0; m < 4; ++m)
#pragma unroll
        for (int n = 0; n < 2; ++n) {
          accg[m][n] = __builtin_amdgcn_mfma_f32_16x16x32_bf16(a[m], bg[n], accg[m][n], 0, 0, 0);
          accu[m][n] = __builtin_amdgcn_mfma_f32_16x16x32_bf16(a[m], bu[n], accu[m][n], 0, 0, 0);
        }
    }
    __syncthreads();
  }

  // epilogue: h = silu(g)*u
#pragma unroll
  for (int m = 0; m < 4; ++m) {
#pragma unroll
    for (int n = 0; n < 2; ++n) {
      int gcol = jbase + wc * 32 + n * 16 + (lane & 15);
#pragma unroll
      for (int j = 0; j < 4; ++j) {
        int r = rowbase + wr * 64 + m * 16 + ((lane >> 4) << 2) + j;
        if (r < ne) {
          float g = accg[m][n][j], u = accu[m][n][j];
          float hv = (g / (1.f + __expf(-g))) * u;
          hbuf[(size_t)(hb + r) * I_DIM + gcol] = __float2bfloat16(hv);
        }
      }
    }
  }
}

// ---------------- GEMM2: out[tok] += w * (h @ W2^T) ----------------
__global__ __launch_bounds__(256, 2) void gemm2_kernel(
    const __hip_bfloat16* __restrict__ hbuf, const __hip_bfloat16* __restrict__ wb2,
    const int* __restrict__ cnt, const int* __restrict__ base,
    const int* __restrict__ idx, const float* __restrict__ wgt,
    float* __restrict__ out)
{
  const int e = blockIdx.z;
  const int ne = cnt[e];
  const int rowbase = blockIdx.y * 128;
  if (rowbase >= ne) return;
  const int nbase = blockIdx.x * 128;
  const int hb = base[e];

  __shared__ short sA[128][64];
  __shared__ short sB[128][64];
  __shared__ int   sTok[128];
  __shared__ float sW[128];

  const int tid = threadIdx.x, wid = tid >> 6, lane = tid & 63;
  const int* idx_e = idx + e * T_TOK;
  const float* wgt_e = wgt + e * T_TOK;

  if (tid < 128) {
    int i = rowbase + tid;
    if (i < ne) { sTok[tid] = idx_e[i]; sW[tid] = wgt_e[i]; }
  }

  const short* hs = (const short*)hbuf;
  const short* w2s = (const short*)wb2 + (size_t)e * H_DIM * I_DIM;

  const short* aSrc[4]; const short* bSrc[4];
#pragma unroll
  for (int it = 0; it < 4; ++it) {
    int ci = it * 4 + wid;
    int off = ci * 512 + lane * 8;
    int row = off >> 6, col = off & 63;
    int i = rowbase + row; if (i > ne - 1) i = ne - 1;
    aSrc[it] = hs + (size_t)(hb + i) * I_DIM + col;
    bSrc[it] = w2s + (size_t)(nbase + row) * I_DIM + col;
  }

  const int wr = wid >> 1, wc = wid & 1;
  f32x4 acc[4][4];
#pragma unroll
  for (int m = 0; m < 4; ++m)
#pragma unroll
    for (int n = 0; n < 4; ++n) acc[m][n] = (f32x4){0,0,0,0};

  for (int k0 = 0; k0 < I_DIM; k0 += 64) {
#pragma unroll
    for (int it = 0; it < 4; ++it) {
      int ci = it * 4 + wid;
      async_copy16((short*)sA + ci * 512, aSrc[it] + k0);
      async_copy16((short*)sB + ci * 512, bSrc[it] + k0);
    }
    __syncthreads();
#pragma unroll
    for (int ks = 0; ks < 2; ++ks) {
      bf16x8 a[4], b[4];
#pragma unroll
      for (int m = 0; m < 4; ++m)
        a[m] = *(const bf16x8*)&sA[wr * 64 + m * 16 + (lane & 15)][ks * 32 + ((lane >> 4) << 3)];
#pragma unroll
      for (int n = 0; n < 4; ++n)
        b[n] = *(const bf16x8*)&sB[wc * 64 + n * 16 + (lane & 15)][ks * 32 + ((lane >> 4) << 3)];
#pragma unroll
      for (int m = 0; m < 4; ++m)
#pragma unroll
        for (int n = 0; n < 4; ++n)
          acc[m][n] = __builtin_amdgcn_mfma_f32_16x16x32_bf16(a[m], b[n], acc[m][n], 0, 0, 0);
    }
    __syncthreads();
  }

#pragma unroll
  for (int m = 0; m < 4; ++m)
#pragma unroll
    for (int n = 0; n < 4; ++n) {
      int gcol = nbase + wc * 64 + n * 16 + (lane & 15);
#pragma unroll
      for (int j = 0; j < 4; ++j) {
        int lr = wr * 64 + m * 16 + ((lane >> 4) << 2) + j;
        if (rowbase + lr < ne) {
          atomicAdd(&out[(size_t)sTok[lr] * H_DIM + gcol], acc[m][n][j] * sW[lr]);
        }
      }
    }
}

// ---------------- launch ----------------
extern "C" void kernel_launch(void* const* d_in, const int* in_sizes, int n_in,
                              void* d_out, int out_size, void* d_ws, size_t ws_size,
                              hipStream_t stream) {
  const float* x  = (const float*)d_in[0];
  const float* gw = (const float*)d_in[1];
  const float* w1 = (const float*)d_in[2];
  const float* w2 = (const float*)d_in[3];
  float* out = (float*)d_out;

  char* ws = (char*)d_ws;
  size_t o = 0;
  __hip_bfloat16* xb   = (__hip_bfloat16*)(ws + o); o += (size_t)T_TOK * H_DIM * 2;        // 33.5MB
  __hip_bfloat16* wb1  = (__hip_bfloat16*)(ws + o); o += (size_t)E_NUM * GU2 * H_DIM * 2;  // 92.3MB
  __hip_bfloat16* wb2  = (__hip_bfloat16*)(ws + o); o += (size_t)E_NUM * H_DIM * I_DIM * 2;// 46.1MB
  __hip_bfloat16* hbuf = (__hip_bfloat16*)(ws + o); o += (size_t)2 * T_TOK * I_DIM * 2;    // 46.1MB
  int*   idx  = (int*)(ws + o);   o += (size_t)E_NUM * T_TOK * 4;
  float* wgt  = (float*)(ws + o); o += (size_t)E_NUM * T_TOK * 4;
  int*   cnt  = (int*)(ws + o);   o += 64;
  int*   base = (int*)(ws + o);   o += 64;

  hipMemsetAsync(out, 0, (size_t)T_TOK * H_DIM * sizeof(float), stream);
  hipMemsetAsync(cnt, 0, 128, stream);  // cnt + base

  cvt_kernel<<<2048, 256, 0, stream>>>((const float4*)x,  (ushort4*)xb,  (T_TOK * H_DIM) / 4);
  cvt_kernel<<<4096, 256, 0, stream>>>((const float4*)w1, (ushort4*)wb1, (E_NUM * GU2 * H_DIM) / 4);
  cvt_kernel<<<4096, 256, 0, stream>>>((const float4*)w2, (ushort4*)wb2, (E_NUM * H_DIM * I_DIM) / 4);

  gating_kernel<<<T_TOK / 4, 256, 0, stream>>>(x, gw, cnt, idx, wgt);
  prefix_kernel<<<1, 64, 0, stream>>>(cnt, base);

  dim3 g1(I_DIM / 64, T_TOK / 128, E_NUM);   // 22 x 64 x 8
  gemm1_kernel<<<g1, 256, 0, stream>>>(xb, wb1, cnt, base, idx, hbuf);

  dim3 g2(H_DIM / 128, T_TOK / 128, E_NUM);  // 16 x 64 x 8
  gemm2_kernel<<<g2, 256, 0, stream>>>(hbuf, wb2, cnt, base, idx, wgt, out);
}

// Round 2
// 734.227 us; speedup vs baseline: 1.0390x; 1.0390x over previous
//
#include <hip/hip_runtime.h>
#include <hip/hip_bf16.h>
#include <stdint.h>

#define T_TOK 8192
#define H_DIM 2048
#define I_DIM 1408
#define E_NUM 8
#define GU2   2816   // 2*I

typedef __attribute__((ext_vector_type(8))) short bf16x8;
typedef __attribute__((ext_vector_type(4))) float f32x4;

__device__ __forceinline__ void async_copy16(const void* g, void* lds) {
  __builtin_amdgcn_global_load_lds(
      (const __attribute__((address_space(1))) uint32_t*)g,
      (__attribute__((address_space(3))) uint32_t*)lds, 16, 0, 0);
}

#define PHASE_BAR() asm volatile("s_barrier" ::: "memory")
#define VMCNT0()    asm volatile("s_waitcnt vmcnt(0)" ::: "memory")

// Swizzled LDS read: tile is [256 rows][64 k] bf16, row stride 128B,
// byte ^= (row&7)<<4 spreads the 16-lane column read across all banks.
__device__ __forceinline__ bf16x8 lds_read_swz(const short* tile, int row, int kcol) {
  int byte = (row << 7) + (kcol << 1);
  byte ^= (row & 7) << 4;
  return *(const bf16x8*)((const char*)tile + byte);
}

__device__ __forceinline__ float bfu2f(unsigned short u) {
  union { unsigned int i; float f; } v; v.i = ((unsigned int)u) << 16; return v.f;
}

// ---------------- f32 -> bf16 conversion (vectorized) ----------------
__global__ __launch_bounds__(256) void cvt_kernel(const float4* __restrict__ in,
                                                  ushort4* __restrict__ out, int n4) {
  int i = blockIdx.x * blockDim.x + threadIdx.x;
  int stride = gridDim.x * blockDim.x;
  for (; i < n4; i += stride) {
    float4 v = in[i];
    ushort4 o;
    __hip_bfloat16 b;
    b = __float2bfloat16(v.x); o.x = *reinterpret_cast<unsigned short*>(&b);
    b = __float2bfloat16(v.y); o.y = *reinterpret_cast<unsigned short*>(&b);
    b = __float2bfloat16(v.z); o.z = *reinterpret_cast<unsigned short*>(&b);
    b = __float2bfloat16(v.w); o.w = *reinterpret_cast<unsigned short*>(&b);
    out[i] = o;
  }
}

// ---------------- gating: logits -> softmax -> top2 -> lists + inverse ----------------
__global__ __launch_bounds__(256) void gating_kernel(
    const float* __restrict__ x, const float* __restrict__ gw,
    int* __restrict__ cnt, int* __restrict__ idx, float* __restrict__ wgt,
    int* __restrict__ invE, int* __restrict__ invP) {
  int wave = threadIdx.x >> 6, lane = threadIdx.x & 63;
  int t = blockIdx.x * 4 + wave;
  if (t >= T_TOK) return;
  const float* xr = x + (size_t)t * H_DIM;
  float acc[E_NUM];
#pragma unroll
  for (int e = 0; e < E_NUM; ++e) acc[e] = 0.f;
  for (int k = lane; k < H_DIM; k += 64) {
    float xv = xr[k];
#pragma unroll
    for (int e = 0; e < E_NUM; ++e) acc[e] += xv * gw[e * H_DIM + k];
  }
#pragma unroll
  for (int e = 0; e < E_NUM; ++e) {
    float s = acc[e];
#pragma unroll
    for (int o = 32; o > 0; o >>= 1) s += __shfl_xor(s, o);
    acc[e] = s;
  }
  if (lane == 0) {
    int i1 = 0; float v1 = acc[0];
#pragma unroll
    for (int e = 1; e < E_NUM; ++e) if (acc[e] > v1) { v1 = acc[e]; i1 = e; }
    int i2 = -1; float v2 = -3.4e38f;
#pragma unroll
    for (int e = 0; e < E_NUM; ++e) if (e != i1 && acc[e] > v2) { v2 = acc[e]; i2 = e; }
    float p2 = expf(v2 - v1);
    float winv = 1.f / (1.f + p2);
    float w1 = winv, w2 = p2 * winv;
    int p = atomicAdd(&cnt[i1], 1);
    idx[i1 * T_TOK + p] = t; wgt[i1 * T_TOK + p] = w1;
    invE[2 * t] = i1; invP[2 * t] = p;
    p = atomicAdd(&cnt[i2], 1);
    idx[i2 * T_TOK + p] = t; wgt[i2 * T_TOK + p] = w2;
    invE[2 * t + 1] = i2; invP[2 * t + 1] = p;
  }
}

__global__ void prefix_kernel(const int* __restrict__ cnt, int* __restrict__ base) {
  if (threadIdx.x == 0 && blockIdx.x == 0) {
    int s = 0;
#pragma unroll
    for (int e = 0; e < E_NUM; ++e) { base[e] = s; s += cnt[e]; }
  }
}

// ============================================================================
// GEMM1: 256 rows x 128 h-cols per block. B-tile rows (256) are interleaved:
// group wc (64 rows) = [ gate rows jbase+wc*32..+31 | up rows 1408+jbase+wc*32..+31 ].
// 8 waves (2M x 4N), per-wave 128x64 C. Multi-phase K loop, swizzled LDS,
// prefetch next K-tile at phase 0/1, one vmcnt+barrier per K-tile.
// ============================================================================
__global__ __launch_bounds__(512, 2) void gemm1_kernel(
    const __hip_bfloat16* __restrict__ xb, const __hip_bfloat16* __restrict__ wb1,
    const int* __restrict__ cnt, const int* __restrict__ base, const int* __restrict__ idx,
    __hip_bfloat16* __restrict__ hbuf)
{
  const int e = blockIdx.z;
  const int ne = cnt[e];
  const int rowbase = blockIdx.y * 256;
  if (rowbase >= ne) return;
  const int jbase = blockIdx.x * 128;
  const int hb = base[e];

  __shared__ short sAB[2][2][256 * 64];  // 128 KiB: [buf][A/B][row*64+k]

  const int tid = threadIdx.x, wid = tid >> 6, lane = tid & 63;
  const int wr = wid >> 2, wc = wid & 3;
  const int l15 = lane & 15, lhi = lane >> 4;
  const int* idx_e = idx + e * T_TOK;
  const char* xs = (const char*)xb;
  const char* w1s = (const char*)wb1 + (size_t)e * GU2 * H_DIM * 2;

  // Staging source pointers (swizzle pre-applied to global column offset)
  const int cb = ((lane & 7) ^ (lane >> 3)) << 4;
  const char* aSrc[4]; const char* bSrc[4];
#pragma unroll
  for (int q = 0; q < 4; ++q) {
    int r = q * 64 + wid * 8 + (lane >> 3);   // 0..255
    int i = rowbase + r; if (i > ne - 1) i = ne - 1;
    aSrc[q] = xs + (size_t)idx_e[i] * (H_DIM * 2) + cb;
    int s = r & 63;
    int wrow = (s < 32) ? (jbase + q * 32 + s) : (I_DIM + jbase + q * 32 + (s - 32));
    bSrc[q] = w1s + (size_t)wrow * (H_DIM * 2) + cb;
  }

  // prologue: stage K-tile 0 into buf 0
#pragma unroll
  for (int q = 0; q < 4; ++q) {
    async_copy16(aSrc[q], &sAB[0][0][q * 4096 + wid * 512]);
    async_copy16(bSrc[q], &sAB[0][1][q * 4096 + wid * 512]);
  }
  __syncthreads();

  f32x4 acc[8][4];
#pragma unroll
  for (int m = 0; m < 8; ++m)
#pragma unroll
    for (int n = 0; n < 4; ++n) acc[m][n] = (f32x4){0, 0, 0, 0};

  const int NK = H_DIM / 64;  // 32 (even)

  auto iter = [&](const short* Ab, const short* Bb, short* An, short* Bn, int kt) {
    const bool st = (kt + 1 < NK);
    const size_t koff = (size_t)(kt + 1) * 128;
    bf16x8 a[4][2], bg[2][2], bu[2][2];

    // ---- phase 0: stage A-next, read a(mh0)+bg, MFMA Q(0,0) ----
    if (st) {
#pragma unroll
      for (int q = 0; q < 4; ++q)
        async_copy16(aSrc[q] + koff, An + q * 4096 + wid * 512);
    }
#pragma unroll
    for (int m = 0; m < 4; ++m)
#pragma unroll
      for (int ks = 0; ks < 2; ++ks)
        a[m][ks] = lds_read_swz(Ab, wr * 128 + m * 16 + l15, ks * 32 + (lhi << 3));
#pragma unroll
    for (int n = 0; n < 2; ++n)
#pragma unroll
      for (int ks = 0; ks < 2; ++ks)
        bg[n][ks] = lds_read_swz(Bb, wc * 64 + n * 16 + l15, ks * 32 + (lhi << 3));
    PHASE_BAR();
    __builtin_amdgcn_s_setprio(1);
#pragma unroll
    for (int m = 0; m < 4; ++m)
#pragma unroll
      for (int n = 0; n < 2; ++n)
#pragma unroll
        for (int ks = 0; ks < 2; ++ks)
          acc[m][n] = __builtin_amdgcn_mfma_f32_16x16x32_bf16(a[m][ks], bg[n][ks], acc[m][n], 0, 0, 0);
    __builtin_amdgcn_s_setprio(0);
    PHASE_BAR();

    // ---- phase 1: stage B-next, read bu, MFMA Q(0,1) ----
    if (st) {
#pragma unroll
      for (int q = 0; q < 4; ++q)
        async_copy16(bSrc[q] + koff, Bn + q * 4096 + wid * 512);
    }
#pragma unroll
    for (int n = 0; n < 2; ++n)
#pragma unroll
      for (int ks = 0; ks < 2; ++ks)
        bu[n][ks] = lds_read_swz(Bb, wc * 64 + 32 + n * 16 + l15, ks * 32 + (lhi << 3));
    PHASE_BAR();
    __builtin_amdgcn_s_setprio(1);
#pragma unroll
    for (int m = 0; m < 4; ++m)
#pragma unroll
      for (int n = 0; n < 2; ++n)
#pragma unroll
        for (int ks = 0; ks < 2; ++ks)
          acc[m][2 + n] = __builtin_amdgcn_mfma_f32_16x16x32_bf16(a[m][ks], bu[n][ks], acc[m][2 + n], 0, 0, 0);
    __builtin_amdgcn_s_setprio(0);
    PHASE_BAR();

    // ---- phase 2: read a(mh1), MFMA Q(1,1) ----
#pragma unroll
    for (int m = 0; m < 4; ++m)
#pragma unroll
      for (int ks = 0; ks < 2; ++ks)
        a[m][ks] = lds_read_swz(Ab, wr * 128 + 64 + m * 16 + l15, ks * 32 + (lhi << 3));
    PHASE_BAR();
    __builtin_amdgcn_s_setprio(1);
#pragma unroll
    for (int m = 0; m < 4; ++m)
#pragma unroll
      for (int n = 0; n < 2; ++n)
#pragma unroll
        for (int ks = 0; ks < 2; ++ks)
          acc[4 + m][2 + n] = __builtin_amdgcn_mfma_f32_16x16x32_bf16(a[m][ks], bu[n][ks], acc[4 + m][2 + n], 0, 0, 0);
    __builtin_amdgcn_s_setprio(0);
    PHASE_BAR();

    // ---- phase 3: MFMA Q(1,0) (bg still live), then K-tile boundary ----
    __builtin_amdgcn_s_setprio(1);
#pragma unroll
    for (int m = 0; m < 4; ++m)
#pragma unroll
      for (int n = 0; n < 2; ++n)
#pragma unroll
        for (int ks = 0; ks < 2; ++ks)
          acc[4 + m][n] = __builtin_amdgcn_mfma_f32_16x16x32_bf16(a[m][ks], bg[n][ks], acc[4 + m][n], 0, 0, 0);
    __builtin_amdgcn_s_setprio(0);
    VMCNT0();
    PHASE_BAR();
  };

  for (int kt = 0; kt < NK; kt += 2) {
    iter(&sAB[0][0][0], &sAB[0][1][0], &sAB[1][0][0], &sAB[1][1][0], kt);
    iter(&sAB[1][0][0], &sAB[1][1][0], &sAB[0][0][0], &sAB[0][1][0], kt + 1);
  }

  // epilogue: h = silu(g)*u
#pragma unroll
  for (int mm = 0; mm < 8; ++mm) {
#pragma unroll
    for (int np = 0; np < 2; ++np) {
      int col = jbase + wc * 32 + np * 16 + l15;
#pragma unroll
      for (int j = 0; j < 4; ++j) {
        int rl = wr * 128 + mm * 16 + lhi * 4 + j;
        int i = rowbase + rl;
        if (i < ne) {
          float g = acc[mm][np][j], u = acc[mm][np + 2][j];
          float hv = (g / (1.f + __expf(-g))) * u;
          hbuf[(size_t)(hb + i) * I_DIM + col] = __float2bfloat16(hv);
        }
      }
    }
  }
}

// ============================================================================
// GEMM2: y[slot] = coef * (h[slot] @ W2^T), written compact to ybuf (bf16).
// 256 rows x 256 cols per block, same schedule as gemm1.
// ============================================================================
__global__ __launch_bounds__(512, 2) void gemm2_kernel(
    const __hip_bfloat16* __restrict__ hbuf, const __hip_bfloat16* __restrict__ wb2,
    const int* __restrict__ cnt, const int* __restrict__ base,
    const float* __restrict__ wgt, __hip_bfloat16* __restrict__ ybuf)
{
  const int e = blockIdx.z;
  const int ne = cnt[e];
  const int rowbase = blockIdx.y * 256;
  if (rowbase >= ne) return;
  const int nbase = blockIdx.x * 256;
  const int hb = base[e];

  __shared__ short sAB[2][2][256 * 64];
  __shared__ float sW[256];

  const int tid = threadIdx.x, wid = tid >> 6, lane = tid & 63;
  const int wr = wid >> 2, wc = wid & 3;
  const int l15 = lane & 15, lhi = lane >> 4;
  const float* wgt_e = wgt + e * T_TOK;
  const char* hs = (const char*)hbuf;
  const char* w2s = (const char*)wb2 + (size_t)e * H_DIM * I_DIM * 2;

  if (tid < 256) {
    int i = rowbase + tid;
    sW[tid] = (i < ne) ? wgt_e[i] : 0.f;
  }

  const int cb = ((lane & 7) ^ (lane >> 3)) << 4;
  const char* aSrc[4]; const char* bSrc[4];
#pragma unroll
  for (int q = 0; q < 4; ++q) {
    int r = q * 64 + wid * 8 + (lane >> 3);
    int i = rowbase + r; if (i > ne - 1) i = ne - 1;
    aSrc[q] = hs + (size_t)(hb + i) * (I_DIM * 2) + cb;
    bSrc[q] = w2s + (size_t)(nbase + r) * (I_DIM * 2) + cb;
  }

#pragma unroll
  for (int q = 0; q < 4; ++q) {
    async_copy16(aSrc[q], &sAB[0][0][q * 4096 + wid * 512]);
    async_copy16(bSrc[q], &sAB[0][1][q * 4096 + wid * 512]);
  }
  __syncthreads();

  f32x4 acc[8][4];
#pragma unroll
  for (int m = 0; m < 8; ++m)
#pragma unroll
    for (int n = 0; n < 4; ++n) acc[m][n] = (f32x4){0, 0, 0, 0};

  const int NK = I_DIM / 64;  // 22 (even)

  auto iter = [&](const short* Ab, const short* Bb, short* An, short* Bn, int kt) {
    const bool st = (kt + 1 < NK);
    const size_t koff = (size_t)(kt + 1) * 128;
    bf16x8 a[4][2], b0[2][2], b1[2][2];

    if (st) {
#pragma unroll
      for (int q = 0; q < 4; ++q)
        async_copy16(aSrc[q] + koff, An + q * 4096 + wid * 512);
    }
#pragma unroll
    for (int m = 0; m < 4; ++m)
#pragma unroll
      for (int ks = 0; ks < 2; ++ks)
        a[m][ks] = lds_read_swz(Ab, wr * 128 + m * 16 + l15, ks * 32 + (lhi << 3));
#pragma unroll
    for (int n = 0; n < 2; ++n)
#pragma unroll
      for (int ks = 0; ks < 2; ++ks)
        b0[n][ks] = lds_read_swz(Bb, wc * 64 + n * 16 + l15, ks * 32 + (lhi << 3));
    PHASE_BAR();
    __builtin_amdgcn_s_setprio(1);
#pragma unroll
    for (int m = 0; m < 4; ++m)
#pragma unroll
      for (int n = 0; n < 2; ++n)
#pragma unroll
        for (int ks = 0; ks < 2; ++ks)
          acc[m][n] = __builtin_amdgcn_mfma_f32_16x16x32_bf16(a[m][ks], b0[n][ks], acc[m][n], 0, 0, 0);
    __builtin_amdgcn_s_setprio(0);
    PHASE_BAR();

    if (st) {
#pragma unroll
      for (int q = 0; q < 4; ++q)
        async_copy16(bSrc[q] + koff, Bn + q * 4096 + wid * 512);
    }
#pragma unroll
    for (int n = 0; n < 2; ++n)
#pragma unroll
      for (int ks = 0; ks < 2; ++ks)
        b1[n][ks] = lds_read_swz(Bb, wc * 64 + 32 + n * 16 + l15, ks * 32 + (lhi << 3));
    PHASE_BAR();
    __builtin_amdgcn_s_setprio(1);
#pragma unroll
    for (int m = 0; m < 4; ++m)
#pragma unroll
      for (int n = 0; n < 2; ++n)
#pragma unroll
        for (int ks = 0; ks < 2; ++ks)
          acc[m][2 + n] = __builtin_amdgcn_mfma_f32_16x16x32_bf16(a[m][ks], b1[n][ks], acc[m][2 + n], 0, 0, 0);
    __builtin_amdgcn_s_setprio(0);
    PHASE_BAR();

#pragma unroll
    for (int m = 0; m < 4; ++m)
#pragma unroll
      for (int ks = 0; ks < 2; ++ks)
        a[m][ks] = lds_read_swz(Ab, wr * 128 + 64 + m * 16 + l15, ks * 32 + (lhi << 3));
    PHASE_BAR();
    __builtin_amdgcn_s_setprio(1);
#pragma unroll
    for (int m = 0; m < 4; ++m)
#pragma unroll
      for (int n = 0; n < 2; ++n)
#pragma unroll
        for (int ks = 0; ks < 2; ++ks)
          acc[4 + m][2 + n] = __builtin_amdgcn_mfma_f32_16x16x32_bf16(a[m][ks], b1[n][ks], acc[4 + m][2 + n], 0, 0, 0);
    __builtin_amdgcn_s_setprio(0);
    PHASE_BAR();

    __builtin_amdgcn_s_setprio(1);
#pragma unroll
    for (int m = 0; m < 4; ++m)
#pragma unroll
      for (int n = 0; n < 2; ++n)
#pragma unroll
        for (int ks = 0; ks < 2; ++ks)
          acc[4 + m][n] = __builtin_amdgcn_mfma_f32_16x16x32_bf16(a[m][ks], b0[n][ks], acc[4 + m][n], 0, 0, 0);
    __builtin_amdgcn_s_setprio(0);
    VMCNT0();
    PHASE_BAR();
  };

  for (int kt = 0; kt < NK; kt += 2) {
    iter(&sAB[0][0][0], &sAB[0][1][0], &sAB[1][0][0], &sAB[1][1][0], kt);
    iter(&sAB[1][0][0], &sAB[1][1][0], &sAB[0][0][0], &sAB[0][1][0], kt + 1);
  }

#pragma unroll
  for (int mm = 0; mm < 8; ++mm) {
#pragma unroll
    for (int nn = 0; nn < 4; ++nn) {
      int col = nbase + wc * 64 + nn * 16 + l15;
#pragma unroll
      for (int j = 0; j < 4; ++j) {
        int rl = wr * 128 + mm * 16 + lhi * 4 + j;
        if (rowbase + rl < ne) {
          float y = acc[mm][nn][j] * sW[rl];
          ybuf[(size_t)(hb + rowbase + rl) * H_DIM + col] = __float2bfloat16(y);
        }
      }
    }
  }
}

// ---------------- combine: out[t] = y[slot1(t)] + y[slot2(t)] ----------------
__global__ __launch_bounds__(256) void combine_kernel(
    const __hip_bfloat16* __restrict__ ybuf, const int* __restrict__ base,
    const int* __restrict__ invE, const int* __restrict__ invP,
    float* __restrict__ out)
{
  int t = blockIdx.x;
  int s1 = base[invE[2 * t]] + invP[2 * t];
  int s2 = base[invE[2 * t + 1]] + invP[2 * t + 1];
  const ushort* y1 = (const ushort*)ybuf + (size_t)s1 * H_DIM;
  const ushort* y2 = (const ushort*)ybuf + (size_t)s2 * H_DIM;
  float* o = out + (size_t)t * H_DIM;
#pragma unroll
  for (int c0 = 0; c0 < H_DIM; c0 += 256 * 4) {
    int c = c0 + threadIdx.x * 4;
    ushort4 a = *(const ushort4*)(y1 + c);
    ushort4 b = *(const ushort4*)(y2 + c);
    float4 r;
    r.x = bfu2f(a.x) + bfu2f(b.x);
    r.y = bfu2f(a.y) + bfu2f(b.y);
    r.z = bfu2f(a.z) + bfu2f(b.z);
    r.w = bfu2f(a.w) + bfu2f(b.w);
    *(float4*)(o + c) = r;
  }
}

// ---------------- launch ----------------
extern "C" void kernel_launch(void* const* d_in, const int* in_sizes, int n_in,
                              void* d_out, int out_size, void* d_ws, size_t ws_size,
                              hipStream_t stream) {
  const float* x  = (const float*)d_in[0];
  const float* gw = (const float*)d_in[1];
  const float* w1 = (const float*)d_in[2];
  const float* w2 = (const float*)d_in[3];
  float* out = (float*)d_out;

  char* ws = (char*)d_ws;
  size_t o = 0;
  __hip_bfloat16* xb   = (__hip_bfloat16*)(ws + o); o += (size_t)T_TOK * H_DIM * 2;         // 33.5MB
  __hip_bfloat16* wb1  = (__hip_bfloat16*)(ws + o); o += (size_t)E_NUM * GU2 * H_DIM * 2;   // 92.3MB
  __hip_bfloat16* wb2  = (__hip_bfloat16*)(ws + o); o += (size_t)E_NUM * H_DIM * I_DIM * 2; // 46.1MB
  __hip_bfloat16* hbuf = (__hip_bfloat16*)(ws + o); o += (size_t)2 * T_TOK * I_DIM * 2;     // 46.1MB
  int*   idx  = (int*)(ws + o);   o += (size_t)E_NUM * T_TOK * 4;
  float* wgt  = (float*)(ws + o); o += (size_t)E_NUM * T_TOK * 4;
  int*   invE = (int*)(ws + o);   o += (size_t)2 * T_TOK * 4;
  int*   invP = (int*)(ws + o);   o += (size_t)2 * T_TOK * 4;
  int*   cnt  = (int*)(ws + o);   o += 64;
  int*   base = (int*)(ws + o);   o += 64;
  // ybuf (67.1MB bf16) aliases wb1 (92.3MB): wb1 is dead once gemm1 completes,
  // and the stream serializes gemm1 -> gemm2.
  __hip_bfloat16* ybuf = wb1;

  hipMemsetAsync(cnt, 0, 128, stream);  // cnt + base

  cvt_kernel<<<2048, 256, 0, stream>>>((const float4*)x,  (ushort4*)xb,  (T_TOK * H_DIM) / 4);
  cvt_kernel<<<4096, 256, 0, stream>>>((const float4*)w1, (ushort4*)wb1, (E_NUM * GU2 * H_DIM) / 4);
  cvt_kernel<<<4096, 256, 0, stream>>>((const float4*)w2, (ushort4*)wb2, (E_NUM * H_DIM * I_DIM) / 4);

  gating_kernel<<<T_TOK / 4, 256, 0, stream>>>(x, gw, cnt, idx, wgt, invE, invP);
  prefix_kernel<<<1, 64, 0, stream>>>(cnt, base);

  dim3 g1(I_DIM / 128, T_TOK / 256, E_NUM);   // 11 x 32 x 8
  gemm1_kernel<<<g1, 512, 0, stream>>>(xb, wb1, cnt, base, idx, hbuf);

  dim3 g2(H_DIM / 256, T_TOK / 256, E_NUM);   // 8 x 32 x 8
  gemm2_kernel<<<g2, 512, 0, stream>>>(hbuf, wb2, cnt, base, wgt, ybuf);

  combine_kernel<<<T_TOK, 256, 0, stream>>>(ybuf, base, invE, invP, out);
}

// Round 3
// 683.566 us; speedup vs baseline: 1.1160x; 1.0741x over previous
//
#include <hip/hip_runtime.h>
#include <hip/hip_bf16.h>
#include <stdint.h>

#define T_TOK 8192
#define H_DIM 2048
#define I_DIM 1408
#define E_NUM 8
#define GU2   2816   // 2*I

typedef __attribute__((ext_vector_type(8))) short bf16x8;
typedef __attribute__((ext_vector_type(4))) float f32x4;

__device__ __forceinline__ void async_copy16(const void* g, void* lds) {
  __builtin_amdgcn_global_load_lds(
      (const __attribute__((address_space(1))) uint32_t*)g,
      (__attribute__((address_space(3))) uint32_t*)lds, 16, 0, 0);
}

#define PHASE_BAR() asm volatile("s_barrier" ::: "memory")
#define WAIT_VM(n)  asm volatile("s_waitcnt vmcnt(" #n ")" ::: "memory")

// Swizzled LDS read: tile is [256 rows][64 k] bf16, row stride 128B,
// byte ^= (row&7)<<4 spreads the 16-lane column read across all banks.
__device__ __forceinline__ bf16x8 lds_read_swz(const short* tile, int row, int kcol) {
  int byte = (row << 7) + (kcol << 1);
  byte ^= (row & 7) << 4;
  return *(const bf16x8*)((const char*)tile + byte);
}

__device__ __forceinline__ float bfu2f(unsigned short u) {
  union { unsigned int i; float f; } v; v.i = ((unsigned int)u) << 16; return v.f;
}

// ---------------- f32 -> bf16 conversion (weights) ----------------
__global__ __launch_bounds__(256) void cvt_kernel(const float4* __restrict__ in,
                                                  ushort4* __restrict__ out, int n4) {
  int i = blockIdx.x * blockDim.x + threadIdx.x;
  int stride = gridDim.x * blockDim.x;
  for (; i < n4; i += stride) {
    float4 v = in[i];
    ushort4 o;
    __hip_bfloat16 b;
    b = __float2bfloat16(v.x); o.x = *reinterpret_cast<unsigned short*>(&b);
    b = __float2bfloat16(v.y); o.y = *reinterpret_cast<unsigned short*>(&b);
    b = __float2bfloat16(v.z); o.z = *reinterpret_cast<unsigned short*>(&b);
    b = __float2bfloat16(v.w); o.w = *reinterpret_cast<unsigned short*>(&b);
    out[i] = o;
  }
}

// ---------- gating: logits -> top2 -> lists + inverse; also writes xb ----------
__global__ __launch_bounds__(256) void gating_kernel(
    const float* __restrict__ x, const float* __restrict__ gw,
    int* __restrict__ cnt, int* __restrict__ idx, float* __restrict__ wgt,
    int* __restrict__ invE, int* __restrict__ invP,
    __hip_bfloat16* __restrict__ xb) {
  int wave = threadIdx.x >> 6, lane = threadIdx.x & 63;
  int t = blockIdx.x * 4 + wave;
  if (t >= T_TOK) return;
  const float4* xr = (const float4*)(x + (size_t)t * H_DIM);
  ushort4* xo = (ushort4*)((unsigned short*)xb + (size_t)t * H_DIM);
  float acc[E_NUM];
#pragma unroll
  for (int e = 0; e < E_NUM; ++e) acc[e] = 0.f;
#pragma unroll
  for (int i = 0; i < H_DIM / 256; ++i) {   // 8 iters, float4 per lane
    int c = i * 64 + lane;
    float4 xv = xr[c];
    ushort4 o;
    __hip_bfloat16 b;
    b = __float2bfloat16(xv.x); o.x = *reinterpret_cast<unsigned short*>(&b);
    b = __float2bfloat16(xv.y); o.y = *reinterpret_cast<unsigned short*>(&b);
    b = __float2bfloat16(xv.z); o.z = *reinterpret_cast<unsigned short*>(&b);
    b = __float2bfloat16(xv.w); o.w = *reinterpret_cast<unsigned short*>(&b);
    xo[c] = o;
#pragma unroll
    for (int e = 0; e < E_NUM; ++e) {
      float4 g = ((const float4*)(gw + (size_t)e * H_DIM))[c];
      acc[e] += xv.x * g.x + xv.y * g.y + xv.z * g.z + xv.w * g.w;
    }
  }
#pragma unroll
  for (int e = 0; e < E_NUM; ++e) {
    float s = acc[e];
#pragma unroll
    for (int o = 32; o > 0; o >>= 1) s += __shfl_xor(s, o);
    acc[e] = s;
  }
  if (lane == 0) {
    int i1 = 0; float v1 = acc[0];
#pragma unroll
    for (int e = 1; e < E_NUM; ++e) if (acc[e] > v1) { v1 = acc[e]; i1 = e; }
    int i2 = -1; float v2 = -3.4e38f;
#pragma unroll
    for (int e = 0; e < E_NUM; ++e) if (e != i1 && acc[e] > v2) { v2 = acc[e]; i2 = e; }
    float p2 = expf(v2 - v1);
    float winv = 1.f / (1.f + p2);
    float w1 = winv, w2 = p2 * winv;
    int p = atomicAdd(&cnt[i1], 1);
    idx[i1 * T_TOK + p] = t; wgt[i1 * T_TOK + p] = w1;
    invE[2 * t] = i1; invP[2 * t] = p;
    p = atomicAdd(&cnt[i2], 1);
    idx[i2 * T_TOK + p] = t; wgt[i2 * T_TOK + p] = w2;
    invE[2 * t + 1] = i2; invP[2 * t + 1] = p;
  }
}

__global__ void prefix_kernel(const int* __restrict__ cnt, int* __restrict__ base) {
  if (threadIdx.x == 0 && blockIdx.x == 0) {
    int s = 0;
#pragma unroll
    for (int e = 0; e < E_NUM; ++e) { base[e] = s; s += cnt[e]; }
  }
}

// ============================================================================
// GEMM1: 256 rows x 128 h-cols. Counted-vmcnt pipeline: stages for tile t+2
// issued during phases 3/4 of tile t; boundary waits vmcnt(8) (t+1's loads),
// leaving t+2's 8 in flight. Full-tile (~4 phase) latency cover.
// ============================================================================
__global__ __launch_bounds__(512, 2) void gemm1_kernel(
    const __hip_bfloat16* __restrict__ xb, const __hip_bfloat16* __restrict__ wb1,
    const int* __restrict__ cnt, const int* __restrict__ base, const int* __restrict__ idx,
    __hip_bfloat16* __restrict__ hbuf)
{
  // XCD swizzle: 2816 blocks, 352/expert -> each XCD owns one expert
  int lin = blockIdx.x;
  int swz = (lin & 7) * (2816 / 8) + (lin >> 3);
  int e = swz / 352; int rem = swz - e * 352;
  int by = rem / 11; int bx = rem - by * 11;
  const int ne = cnt[e];
  const int rowbase = by * 256;
  if (rowbase >= ne) return;
  const int jbase = bx * 128;
  const int hb = base[e];

  __shared__ short sA[2][256 * 64];
  __shared__ short sB[2][256 * 64];

  const int tid = threadIdx.x, wid = tid >> 6, lane = tid & 63;
  const int wr = wid >> 2, wc = wid & 3;
  const int l15 = lane & 15, lhi = lane >> 4;
  const int* idx_e = idx + e * T_TOK;
  const char* xs = (const char*)xb;
  const char* w1s = (const char*)wb1 + (size_t)e * GU2 * H_DIM * 2;

  const int cb = ((lane & 7) ^ (lane >> 3)) << 4;  // pre-swizzled source col
  const char* aSrc[4]; const char* bSrc[4];
#pragma unroll
  for (int q = 0; q < 4; ++q) {
    int r = q * 64 + wid * 8 + (lane >> 3);
    int i = rowbase + r; if (i > ne - 1) i = ne - 1;
    aSrc[q] = xs + (size_t)idx_e[i] * (H_DIM * 2) + cb;
    int s = r & 63;
    int wrow = (s < 32) ? (jbase + q * 32 + s) : (I_DIM + jbase + q * 32 + (s - 32));
    bSrc[q] = w1s + (size_t)wrow * (H_DIM * 2) + cb;
  }

  // prologue: stage tiles 0 and 1; wait for tile 0 only
#pragma unroll
  for (int q = 0; q < 4; ++q) async_copy16(bSrc[q], &sB[0][q * 4096 + wid * 512]);
#pragma unroll
  for (int q = 0; q < 4; ++q) async_copy16(aSrc[q], &sA[0][q * 4096 + wid * 512]);
#pragma unroll
  for (int q = 0; q < 4; ++q) async_copy16(bSrc[q] + 128, &sB[1][q * 4096 + wid * 512]);
#pragma unroll
  for (int q = 0; q < 4; ++q) async_copy16(aSrc[q] + 128, &sA[1][q * 4096 + wid * 512]);
  WAIT_VM(8);
  PHASE_BAR();

  f32x4 acc[8][4];
#pragma unroll
  for (int m = 0; m < 8; ++m)
#pragma unroll
    for (int n = 0; n < 4; ++n) acc[m][n] = (f32x4){0, 0, 0, 0};

  const int NK = H_DIM / 64;  // 32

  auto iter = [&](short* curA, short* curB, int t) {
    const bool st = (t + 2 < NK);
    const size_t koff = (size_t)(t + 2) * 128;
    bf16x8 a[4][2], bg[2][2], bu[2][2];

    // phase 1: read a-lo + bg; MFMA Q(lo,g)
#pragma unroll
    for (int m = 0; m < 4; ++m)
#pragma unroll
      for (int ks = 0; ks < 2; ++ks)
        a[m][ks] = lds_read_swz(curA, wr * 128 + m * 16 + l15, ks * 32 + (lhi << 3));
#pragma unroll
    for (int n = 0; n < 2; ++n)
#pragma unroll
      for (int ks = 0; ks < 2; ++ks)
        bg[n][ks] = lds_read_swz(curB, wc * 64 + n * 16 + l15, ks * 32 + (lhi << 3));
    PHASE_BAR();
    __builtin_amdgcn_s_setprio(1);
#pragma unroll
    for (int m = 0; m < 4; ++m)
#pragma unroll
      for (int n = 0; n < 2; ++n)
#pragma unroll
        for (int ks = 0; ks < 2; ++ks)
          acc[m][n] = __builtin_amdgcn_mfma_f32_16x16x32_bf16(a[m][ks], bg[n][ks], acc[m][n], 0, 0, 0);
    __builtin_amdgcn_s_setprio(0);
    PHASE_BAR();

    // phase 2: read bu; MFMA Q(lo,u)
#pragma unroll
    for (int n = 0; n < 2; ++n)
#pragma unroll
      for (int ks = 0; ks < 2; ++ks)
        bu[n][ks] = lds_read_swz(curB, wc * 64 + 32 + n * 16 + l15, ks * 32 + (lhi << 3));
    PHASE_BAR();
    __builtin_amdgcn_s_setprio(1);
#pragma unroll
    for (int m = 0; m < 4; ++m)
#pragma unroll
      for (int n = 0; n < 2; ++n)
#pragma unroll
        for (int ks = 0; ks < 2; ++ks)
          acc[m][2 + n] = __builtin_amdgcn_mfma_f32_16x16x32_bf16(a[m][ks], bu[n][ks], acc[m][2 + n], 0, 0, 0);
    __builtin_amdgcn_s_setprio(0);
    PHASE_BAR();

    // phase 3: read a-hi; stage B(t+2) into curB (B reads of cur all landed); MFMA Q(hi,u)
#pragma unroll
    for (int m = 0; m < 4; ++m)
#pragma unroll
      for (int ks = 0; ks < 2; ++ks)
        a[m][ks] = lds_read_swz(curA, wr * 128 + 64 + m * 16 + l15, ks * 32 + (lhi << 3));
    PHASE_BAR();
    if (st) {
#pragma unroll
      for (int q = 0; q < 4; ++q)
        async_copy16(bSrc[q] + koff, curB + q * 4096 + wid * 512);
    }
    __builtin_amdgcn_s_setprio(1);
#pragma unroll
    for (int m = 0; m < 4; ++m)
#pragma unroll
      for (int n = 0; n < 2; ++n)
#pragma unroll
        for (int ks = 0; ks < 2; ++ks)
          acc[4 + m][2 + n] = __builtin_amdgcn_mfma_f32_16x16x32_bf16(a[m][ks], bu[n][ks], acc[4 + m][2 + n], 0, 0, 0);
    __builtin_amdgcn_s_setprio(0);
    PHASE_BAR();

    // phase 4: stage A(t+2) into curA (A reads of cur all landed); MFMA Q(hi,g)
    if (st) {
#pragma unroll
      for (int q = 0; q < 4; ++q)
        async_copy16(aSrc[q] + koff, curA + q * 4096 + wid * 512);
    }
    __builtin_amdgcn_s_setprio(1);
#pragma unroll
    for (int m = 0; m < 4; ++m)
#pragma unroll
      for (int n = 0; n < 2; ++n)
#pragma unroll
        for (int ks = 0; ks < 2; ++ks)
          acc[4 + m][n] = __builtin_amdgcn_mfma_f32_16x16x32_bf16(a[m][ks], bg[n][ks], acc[4 + m][n], 0, 0, 0);
    __builtin_amdgcn_s_setprio(0);

    // boundary: drain tile t+1's loads only (counted), keep t+2's in flight
    if (t + 1 < NK) {
      if (st) { WAIT_VM(8); } else { WAIT_VM(0); }
      PHASE_BAR();
    }
  };

  for (int t = 0; t < NK; t += 2) {
    iter(&sA[0][0], &sB[0][0], t);
    iter(&sA[1][0], &sB[1][0], t + 1);
  }

  // epilogue: h = silu(g)*u
#pragma unroll
  for (int mm = 0; mm < 8; ++mm) {
#pragma unroll
    for (int np = 0; np < 2; ++np) {
      int col = jbase + wc * 32 + np * 16 + l15;
#pragma unroll
      for (int j = 0; j < 4; ++j) {
        int rl = wr * 128 + mm * 16 + lhi * 4 + j;
        int i = rowbase + rl;
        if (i < ne) {
          float g = acc[mm][np][j], u = acc[mm][np + 2][j];
          float hv = (g / (1.f + __expf(-g))) * u;
          hbuf[(size_t)(hb + i) * I_DIM + col] = __float2bfloat16(hv);
        }
      }
    }
  }
}

// ============================================================================
// GEMM2: y[slot] = coef * (h[slot] @ W2^T), compact bf16 ybuf. Same pipeline.
// ============================================================================
__global__ __launch_bounds__(512, 2) void gemm2_kernel(
    const __hip_bfloat16* __restrict__ hbuf, const __hip_bfloat16* __restrict__ wb2,
    const int* __restrict__ cnt, const int* __restrict__ base,
    const float* __restrict__ wgt, __hip_bfloat16* __restrict__ ybuf)
{
  // XCD swizzle: 2048 blocks, 256/expert -> each XCD owns one expert
  int lin = blockIdx.x;
  int swz = (lin & 7) * 256 + (lin >> 3);
  int e = swz >> 8; int rem = swz & 255;
  int by = rem >> 3; int bx = rem & 7;
  const int ne = cnt[e];
  const int rowbase = by * 256;
  if (rowbase >= ne) return;
  const int nbase = bx * 256;
  const int hb = base[e];

  __shared__ short sA[2][256 * 64];
  __shared__ short sB[2][256 * 64];
  __shared__ float sW[256];

  const int tid = threadIdx.x, wid = tid >> 6, lane = tid & 63;
  const int wr = wid >> 2, wc = wid & 3;
  const int l15 = lane & 15, lhi = lane >> 4;
  const float* wgt_e = wgt + e * T_TOK;
  const char* hs = (const char*)hbuf;
  const char* w2s = (const char*)wb2 + (size_t)e * H_DIM * I_DIM * 2;

  if (tid < 256) {
    int i = rowbase + tid;
    sW[tid] = (i < ne) ? wgt_e[i] : 0.f;
  }

  const int cb = ((lane & 7) ^ (lane >> 3)) << 4;
  const char* aSrc[4]; const char* bSrc[4];
#pragma unroll
  for (int q = 0; q < 4; ++q) {
    int r = q * 64 + wid * 8 + (lane >> 3);
    int i = rowbase + r; if (i > ne - 1) i = ne - 1;
    aSrc[q] = hs + (size_t)(hb + i) * (I_DIM * 2) + cb;
    bSrc[q] = w2s + (size_t)(nbase + r) * (I_DIM * 2) + cb;
  }

#pragma unroll
  for (int q = 0; q < 4; ++q) async_copy16(bSrc[q], &sB[0][q * 4096 + wid * 512]);
#pragma unroll
  for (int q = 0; q < 4; ++q) async_copy16(aSrc[q], &sA[0][q * 4096 + wid * 512]);
#pragma unroll
  for (int q = 0; q < 4; ++q) async_copy16(bSrc[q] + 128, &sB[1][q * 4096 + wid * 512]);
#pragma unroll
  for (int q = 0; q < 4; ++q) async_copy16(aSrc[q] + 128, &sA[1][q * 4096 + wid * 512]);
  WAIT_VM(8);
  PHASE_BAR();

  f32x4 acc[8][4];
#pragma unroll
  for (int m = 0; m < 8; ++m)
#pragma unroll
    for (int n = 0; n < 4; ++n) acc[m][n] = (f32x4){0, 0, 0, 0};

  const int NK = I_DIM / 64;  // 22

  auto iter = [&](short* curA, short* curB, int t) {
    const bool st = (t + 2 < NK);
    const size_t koff = (size_t)(t + 2) * 128;
    bf16x8 a[4][2], b0[2][2], b1[2][2];

#pragma unroll
    for (int m = 0; m < 4; ++m)
#pragma unroll
      for (int ks = 0; ks < 2; ++ks)
        a[m][ks] = lds_read_swz(curA, wr * 128 + m * 16 + l15, ks * 32 + (lhi << 3));
#pragma unroll
    for (int n = 0; n < 2; ++n)
#pragma unroll
      for (int ks = 0; ks < 2; ++ks)
        b0[n][ks] = lds_read_swz(curB, wc * 64 + n * 16 + l15, ks * 32 + (lhi << 3));
    PHASE_BAR();
    __builtin_amdgcn_s_setprio(1);
#pragma unroll
    for (int m = 0; m < 4; ++m)
#pragma unroll
      for (int n = 0; n < 2; ++n)
#pragma unroll
        for (int ks = 0; ks < 2; ++ks)
          acc[m][n] = __builtin_amdgcn_mfma_f32_16x16x32_bf16(a[m][ks], b0[n][ks], acc[m][n], 0, 0, 0);
    __builtin_amdgcn_s_setprio(0);
    PHASE_BAR();

#pragma unroll
    for (int n = 0; n < 2; ++n)
#pragma unroll
      for (int ks = 0; ks < 2; ++ks)
        b1[n][ks] = lds_read_swz(curB, wc * 64 + 32 + n * 16 + l15, ks * 32 + (lhi << 3));
    PHASE_BAR();
    __builtin_amdgcn_s_setprio(1);
#pragma unroll
    for (int m = 0; m < 4; ++m)
#pragma unroll
      for (int n = 0; n < 2; ++n)
#pragma unroll
        for (int ks = 0; ks < 2; ++ks)
          acc[m][2 + n] = __builtin_amdgcn_mfma_f32_16x16x32_bf16(a[m][ks], b1[n][ks], acc[m][2 + n], 0, 0, 0);
    __builtin_amdgcn_s_setprio(0);
    PHASE_BAR();

#pragma unroll
    for (int m = 0; m < 4; ++m)
#pragma unroll
      for (int ks = 0; ks < 2; ++ks)
        a[m][ks] = lds_read_swz(curA, wr * 128 + 64 + m * 16 + l15, ks * 32 + (lhi << 3));
    PHASE_BAR();
    if (st) {
#pragma unroll
      for (int q = 0; q < 4; ++q)
        async_copy16(bSrc[q] + koff, curB + q * 4096 + wid * 512);
    }
    __builtin_amdgcn_s_setprio(1);
#pragma unroll
    for (int m = 0; m < 4; ++m)
#pragma unroll
      for (int n = 0; n < 2; ++n)
#pragma unroll
        for (int ks = 0; ks < 2; ++ks)
          acc[4 + m][2 + n] = __builtin_amdgcn_mfma_f32_16x16x32_bf16(a[m][ks], b1[n][ks], acc[4 + m][2 + n], 0, 0, 0);
    __builtin_amdgcn_s_setprio(0);
    PHASE_BAR();

    if (st) {
#pragma unroll
      for (int q = 0; q < 4; ++q)
        async_copy16(aSrc[q] + koff, curA + q * 4096 + wid * 512);
    }
    __builtin_amdgcn_s_setprio(1);
#pragma unroll
    for (int m = 0; m < 4; ++m)
#pragma unroll
      for (int n = 0; n < 2; ++n)
#pragma unroll
        for (int ks = 0; ks < 2; ++ks)
          acc[4 + m][n] = __builtin_amdgcn_mfma_f32_16x16x32_bf16(a[m][ks], b0[n][ks], acc[4 + m][n], 0, 0, 0);
    __builtin_amdgcn_s_setprio(0);

    if (t + 1 < NK) {
      if (st) { WAIT_VM(8); } else { WAIT_VM(0); }
      PHASE_BAR();
    }
  };

  for (int t = 0; t < NK; t += 2) {
    iter(&sA[0][0], &sB[0][0], t);
    iter(&sA[1][0], &sB[1][0], t + 1);
  }

#pragma unroll
  for (int mm = 0; mm < 8; ++mm) {
#pragma unroll
    for (int nn = 0; nn < 4; ++nn) {
      int col = nbase + wc * 64 + nn * 16 + l15;
#pragma unroll
      for (int j = 0; j < 4; ++j) {
        int rl = wr * 128 + mm * 16 + lhi * 4 + j;
        if (rowbase + rl < ne) {
          float y = acc[mm][nn][j] * sW[rl];
          ybuf[(size_t)(hb + rowbase + rl) * H_DIM + col] = __float2bfloat16(y);
        }
      }
    }
  }
}

// ---------------- combine: out[t] = y[slot1(t)] + y[slot2(t)] ----------------
__global__ __launch_bounds__(256) void combine_kernel(
    const __hip_bfloat16* __restrict__ ybuf, const int* __restrict__ base,
    const int* __restrict__ invE, const int* __restrict__ invP,
    float* __restrict__ out)
{
  int t = blockIdx.x;
  int s1 = base[invE[2 * t]] + invP[2 * t];
  int s2 = base[invE[2 * t + 1]] + invP[2 * t + 1];
  const ushort* y1 = (const ushort*)ybuf + (size_t)s1 * H_DIM;
  const ushort* y2 = (const ushort*)ybuf + (size_t)s2 * H_DIM;
  float* o = out + (size_t)t * H_DIM;
#pragma unroll
  for (int c0 = 0; c0 < H_DIM; c0 += 256 * 4) {
    int c = c0 + threadIdx.x * 4;
    ushort4 a = *(const ushort4*)(y1 + c);
    ushort4 b = *(const ushort4*)(y2 + c);
    float4 r;
    r.x = bfu2f(a.x) + bfu2f(b.x);
    r.y = bfu2f(a.y) + bfu2f(b.y);
    r.z = bfu2f(a.z) + bfu2f(b.z);
    r.w = bfu2f(a.w) + bfu2f(b.w);
    *(float4*)(o + c) = r;
  }
}

// ---------------- launch ----------------
extern "C" void kernel_launch(void* const* d_in, const int* in_sizes, int n_in,
                              void* d_out, int out_size, void* d_ws, size_t ws_size,
                              hipStream_t stream) {
  const float* x  = (const float*)d_in[0];
  const float* gw = (const float*)d_in[1];
  const float* w1 = (const float*)d_in[2];
  const float* w2 = (const float*)d_in[3];
  float* out = (float*)d_out;

  char* ws = (char*)d_ws;
  size_t o = 0;
  __hip_bfloat16* xb   = (__hip_bfloat16*)(ws + o); o += (size_t)T_TOK * H_DIM * 2;         // 33.5MB
  __hip_bfloat16* wb1  = (__hip_bfloat16*)(ws + o); o += (size_t)E_NUM * GU2 * H_DIM * 2;   // 92.3MB
  __hip_bfloat16* wb2  = (__hip_bfloat16*)(ws + o); o += (size_t)E_NUM * H_DIM * I_DIM * 2; // 46.1MB
  __hip_bfloat16* hbuf = (__hip_bfloat16*)(ws + o); o += (size_t)2 * T_TOK * I_DIM * 2;     // 46.1MB
  int*   idx  = (int*)(ws + o);   o += (size_t)E_NUM * T_TOK * 4;
  float* wgt  = (float*)(ws + o); o += (size_t)E_NUM * T_TOK * 4;
  int*   invE = (int*)(ws + o);   o += (size_t)2 * T_TOK * 4;
  int*   invP = (int*)(ws + o);   o += (size_t)2 * T_TOK * 4;
  int*   cnt  = (int*)(ws + o);   o += 64;
  int*   base = (int*)(ws + o);   o += 64;
  // ybuf (67.1MB bf16) aliases xb+wb1 (125.8MB): both dead once gemm1 completes.
  __hip_bfloat16* ybuf = (__hip_bfloat16*)ws;

  hipMemsetAsync(cnt, 0, 128, stream);  // cnt + base

  cvt_kernel<<<4096, 256, 0, stream>>>((const float4*)w1, (ushort4*)wb1, (E_NUM * GU2 * H_DIM) / 4);
  cvt_kernel<<<4096, 256, 0, stream>>>((const float4*)w2, (ushort4*)wb2, (E_NUM * H_DIM * I_DIM) / 4);

  gating_kernel<<<T_TOK / 4, 256, 0, stream>>>(x, gw, cnt, idx, wgt, invE, invP, xb);
  prefix_kernel<<<1, 64, 0, stream>>>(cnt, base);

  gemm1_kernel<<<dim3(2816), 512, 0, stream>>>(xb, wb1, cnt, base, idx, hbuf);
  gemm2_kernel<<<dim3(2048), 512, 0, stream>>>(hbuf, wb2, cnt, base, wgt, ybuf);

  combine_kernel<<<T_TOK, 256, 0, stream>>>(ybuf, base, invE, invP, out);
}

// Round 4
// 666.069 us; speedup vs baseline: 1.1454x; 1.0263x over previous
//
#include <hip/hip_runtime.h>
#include <hip/hip_bf16.h>
#include <stdint.h>

#define T_TOK 8192
#define H_DIM 2048
#define I_DIM 1408
#define E_NUM 8
#define GU2   2816   // 2*I

typedef __attribute__((ext_vector_type(8))) short bf16x8;
typedef __attribute__((ext_vector_type(4))) float f32x4;

__device__ __forceinline__ void async_copy16(const void* g, void* lds) {
  __builtin_amdgcn_global_load_lds(
      (const __attribute__((address_space(1))) uint32_t*)g,
      (__attribute__((address_space(3))) uint32_t*)lds, 16, 0, 0);
}

#define PHASE_BAR() asm volatile("s_barrier" ::: "memory")
#define WAIT_VM(n)  asm volatile("s_waitcnt vmcnt(" #n ")" ::: "memory")

// Swizzled LDS read: tile is [256 rows][64 k] bf16, row stride 128B,
// byte ^= (row&7)<<4 spreads the 16-lane column read across all banks.
__device__ __forceinline__ bf16x8 lds_read_swz(const short* tile, int row, int kcol) {
  int byte = (row << 7) + (kcol << 1);
  byte ^= (row & 7) << 4;
  return *(const bf16x8*)((const char*)tile + byte);
}

__device__ __forceinline__ float bfu2f(unsigned short u) {
  union { unsigned int i; float f; } v; v.i = ((unsigned int)u) << 16; return v.f;
}

// ---------------- f32 -> bf16 conversion (weights) ----------------
__global__ __launch_bounds__(256) void cvt_kernel(const float4* __restrict__ in,
                                                  ushort4* __restrict__ out, int n4) {
  int i = blockIdx.x * blockDim.x + threadIdx.x;
  int stride = gridDim.x * blockDim.x;
  for (; i < n4; i += stride) {
    float4 v = in[i];
    ushort4 o;
    __hip_bfloat16 b;
    b = __float2bfloat16(v.x); o.x = *reinterpret_cast<unsigned short*>(&b);
    b = __float2bfloat16(v.y); o.y = *reinterpret_cast<unsigned short*>(&b);
    b = __float2bfloat16(v.z); o.z = *reinterpret_cast<unsigned short*>(&b);
    b = __float2bfloat16(v.w); o.w = *reinterpret_cast<unsigned short*>(&b);
    out[i] = o;
  }
}

// ---------- gating: logits -> top2 -> lists + inverse; also writes xb ----------
__global__ __launch_bounds__(256) void gating_kernel(
    const float* __restrict__ x, const float* __restrict__ gw,
    int* __restrict__ cnt, int* __restrict__ idx, float* __restrict__ wgt,
    int* __restrict__ invE, int* __restrict__ invP,
    __hip_bfloat16* __restrict__ xb) {
  int wave = threadIdx.x >> 6, lane = threadIdx.x & 63;
  int t = blockIdx.x * 4 + wave;
  if (t >= T_TOK) return;
  const float4* xr = (const float4*)(x + (size_t)t * H_DIM);
  ushort4* xo = (ushort4*)((unsigned short*)xb + (size_t)t * H_DIM);
  float acc[E_NUM];
#pragma unroll
  for (int e = 0; e < E_NUM; ++e) acc[e] = 0.f;
#pragma unroll
  for (int i = 0; i < H_DIM / 256; ++i) {   // 8 iters, float4 per lane
    int c = i * 64 + lane;
    float4 xv = xr[c];
    ushort4 o;
    __hip_bfloat16 b;
    b = __float2bfloat16(xv.x); o.x = *reinterpret_cast<unsigned short*>(&b);
    b = __float2bfloat16(xv.y); o.y = *reinterpret_cast<unsigned short*>(&b);
    b = __float2bfloat16(xv.z); o.z = *reinterpret_cast<unsigned short*>(&b);
    b = __float2bfloat16(xv.w); o.w = *reinterpret_cast<unsigned short*>(&b);
    xo[c] = o;
#pragma unroll
    for (int e = 0; e < E_NUM; ++e) {
      float4 g = ((const float4*)(gw + (size_t)e * H_DIM))[c];
      acc[e] += xv.x * g.x + xv.y * g.y + xv.z * g.z + xv.w * g.w;
    }
  }
#pragma unroll
  for (int e = 0; e < E_NUM; ++e) {
    float s = acc[e];
#pragma unroll
    for (int o = 32; o > 0; o >>= 1) s += __shfl_xor(s, o);
    acc[e] = s;
  }
  if (lane == 0) {
    int i1 = 0; float v1 = acc[0];
#pragma unroll
    for (int e = 1; e < E_NUM; ++e) if (acc[e] > v1) { v1 = acc[e]; i1 = e; }
    int i2 = -1; float v2 = -3.4e38f;
#pragma unroll
    for (int e = 0; e < E_NUM; ++e) if (e != i1 && acc[e] > v2) { v2 = acc[e]; i2 = e; }
    float p2 = expf(v2 - v1);
    float winv = 1.f / (1.f + p2);
    float w1 = winv, w2 = p2 * winv;
    int p = atomicAdd(&cnt[i1], 1);
    idx[i1 * T_TOK + p] = t; wgt[i1 * T_TOK + p] = w1;
    invE[2 * t] = i1; invP[2 * t] = p;
    p = atomicAdd(&cnt[i2], 1);
    idx[i2 * T_TOK + p] = t; wgt[i2 * T_TOK + p] = w2;
    invE[2 * t + 1] = i2; invP[2 * t + 1] = p;
  }
}

__global__ void prefix_kernel(const int* __restrict__ cnt, int* __restrict__ base) {
  if (threadIdx.x == 0 && blockIdx.x == 0) {
    int s = 0;
#pragma unroll
    for (int e = 0; e < E_NUM; ++e) { base[e] = s; s += cnt[e]; }
  }
}

// ============================================================================
// GEMM1: 256 slot-rows x 128 h-cols (256 B-rows interleaved g|u).
// m201-faithful 8-phase/2-K-tile schedule: per phase read one fragment
// quarter + stage ONE half-tile (2 loads); A staged 1 tile ahead (ph1/2),
// B staged 2 tiles ahead into same-parity buffer (ph3/4, legal: B(t) fully
// consumed after ph2). Boundary: vmcnt(4) — drains A/B(t+1), keeps B(t+2).
// ============================================================================
__global__ __launch_bounds__(512, 2) void gemm1_kernel(
    const __hip_bfloat16* __restrict__ xb, const __hip_bfloat16* __restrict__ wb1,
    const int* __restrict__ cnt, const int* __restrict__ base, const int* __restrict__ idx,
    __hip_bfloat16* __restrict__ hbuf)
{
  // XCD swizzle: 2112 blocks = 8 XCDs x 264 (24 row-blocks x 11 col-blocks)
  int lin = blockIdx.x;
  int swz = (lin & 7) * 264 + (lin >> 3);
  int e = swz / 264; int rem = swz - e * 264;
  int by = rem / 11; int bx = rem - by * 11;
  const int ne = cnt[e];
  const int rowbase = by * 256;
  if (rowbase >= ne) return;
  const int jbase = bx * 128;
  const int hb = base[e];

  __shared__ short sA[2][256 * 64];
  __shared__ short sB[2][256 * 64];

  const int tid = threadIdx.x, wid = tid >> 6, lane = tid & 63;
  const int wr = wid >> 2, wc = wid & 3;
  const int l15 = lane & 15, lhi = lane >> 4;
  const int* idx_e = idx + e * T_TOK;
  const char* xs = (const char*)xb;
  const char* w1s = (const char*)wb1 + (size_t)e * GU2 * H_DIM * 2;

  const int cb = ((lane & 7) ^ (lane >> 3)) << 4;  // pre-swizzled source col
  const char* aSrc[4]; const char* bSrc[4];
#pragma unroll
  for (int q = 0; q < 4; ++q) {
    int r = q * 64 + wid * 8 + (lane >> 3);
    int i = rowbase + r; if (i > ne - 1) i = ne - 1;
    aSrc[q] = xs + (size_t)idx_e[i] * (H_DIM * 2) + cb;
    int s = r & 63;
    int wrow = (s < 32) ? (jbase + q * 32 + s) : (I_DIM + jbase + q * 32 + (s - 32));
    bSrc[q] = w1s + (size_t)wrow * (H_DIM * 2) + cb;
  }

  const int NK = H_DIM / 64;  // 32 (even)

  // prologue: B(0), A(0), B(1), A(1); drain tile-0's 8, keep tile-1's 8
#pragma unroll
  for (int q = 0; q < 4; ++q) async_copy16(bSrc[q], &sB[0][q * 4096 + wid * 512]);
#pragma unroll
  for (int q = 0; q < 4; ++q) async_copy16(aSrc[q], &sA[0][q * 4096 + wid * 512]);
#pragma unroll
  for (int q = 0; q < 4; ++q) async_copy16(bSrc[q] + 128, &sB[1][q * 4096 + wid * 512]);
#pragma unroll
  for (int q = 0; q < 4; ++q) async_copy16(aSrc[q] + 128, &sA[1][q * 4096 + wid * 512]);
  WAIT_VM(8);
  PHASE_BAR();

  f32x4 acc[8][4];
#pragma unroll
  for (int m = 0; m < 8; ++m)
#pragma unroll
    for (int n = 0; n < 4; ++n) acc[m][n] = (f32x4){0, 0, 0, 0};

  auto iter = [&](short* bufA, short* bufB, short* altA, int t) {
    const bool stA = (t >= 1) && (t + 1 < NK);
    const bool stB = (t + 2 < NK);
    const size_t kA = (size_t)(t + 1) * 128;
    const size_t kB = (size_t)(t + 2) * 128;
    bf16x8 a[4][2], bg[2][2], bu[2][2];

    // ---- ph1: read a-lo quarter + bg; stage A-lo(t+1); MFMA Qg-lo ----
#pragma unroll
    for (int m = 0; m < 4; ++m)
#pragma unroll
      for (int ks = 0; ks < 2; ++ks)
        a[m][ks] = lds_read_swz(bufA, wr * 128 + m * 16 + l15, ks * 32 + (lhi << 3));
#pragma unroll
    for (int n = 0; n < 2; ++n)
#pragma unroll
      for (int ks = 0; ks < 2; ++ks)
        bg[n][ks] = lds_read_swz(bufB, wc * 64 + n * 16 + l15, ks * 32 + (lhi << 3));
    if (stA) {
      async_copy16(aSrc[0] + kA, altA + 0 * 4096 + wid * 512);
      async_copy16(aSrc[1] + kA, altA + 1 * 4096 + wid * 512);
    }
    PHASE_BAR();
    __builtin_amdgcn_s_setprio(1);
#pragma unroll
    for (int m = 0; m < 4; ++m)
#pragma unroll
      for (int n = 0; n < 2; ++n)
#pragma unroll
        for (int ks = 0; ks < 2; ++ks)
          acc[m][n] = __builtin_amdgcn_mfma_f32_16x16x32_bf16(a[m][ks], bg[n][ks], acc[m][n], 0, 0, 0);
    __builtin_amdgcn_s_setprio(0);
    PHASE_BAR();

    // ---- ph2: read bu; stage A-hi(t+1); MFMA Qu-lo ----
#pragma unroll
    for (int n = 0; n < 2; ++n)
#pragma unroll
      for (int ks = 0; ks < 2; ++ks)
        bu[n][ks] = lds_read_swz(bufB, wc * 64 + 32 + n * 16 + l15, ks * 32 + (lhi << 3));
    if (stA) {
      async_copy16(aSrc[2] + kA, altA + 2 * 4096 + wid * 512);
      async_copy16(aSrc[3] + kA, altA + 3 * 4096 + wid * 512);
    }
    PHASE_BAR();
    __builtin_amdgcn_s_setprio(1);
#pragma unroll
    for (int m = 0; m < 4; ++m)
#pragma unroll
      for (int n = 0; n < 2; ++n)
#pragma unroll
        for (int ks = 0; ks < 2; ++ks)
          acc[m][2 + n] = __builtin_amdgcn_mfma_f32_16x16x32_bf16(a[m][ks], bu[n][ks], acc[m][2 + n], 0, 0, 0);
    __builtin_amdgcn_s_setprio(0);
    PHASE_BAR();

    // ---- ph3: read a-hi quarter; stage B-lo(t+2) into bufB; MFMA Qu-hi ----
#pragma unroll
    for (int m = 0; m < 4; ++m)
#pragma unroll
      for (int ks = 0; ks < 2; ++ks)
        a[m][ks] = lds_read_swz(bufA, wr * 128 + 64 + m * 16 + l15, ks * 32 + (lhi << 3));
    if (stB) {
      async_copy16(bSrc[0] + kB, bufB + 0 * 4096 + wid * 512);
      async_copy16(bSrc[1] + kB, bufB + 1 * 4096 + wid * 512);
    }
    PHASE_BAR();
    __builtin_amdgcn_s_setprio(1);
#pragma unroll
    for (int m = 0; m < 4; ++m)
#pragma unroll
      for (int n = 0; n < 2; ++n)
#pragma unroll
        for (int ks = 0; ks < 2; ++ks)
          acc[4 + m][2 + n] = __builtin_amdgcn_mfma_f32_16x16x32_bf16(a[m][ks], bu[n][ks], acc[4 + m][2 + n], 0, 0, 0);
    __builtin_amdgcn_s_setprio(0);
    PHASE_BAR();

    // ---- ph4: stage B-hi(t+2); MFMA Qg-hi; boundary vmcnt(4) ----
    if (stB) {
      async_copy16(bSrc[2] + kB, bufB + 2 * 4096 + wid * 512);
      async_copy16(bSrc[3] + kB, bufB + 3 * 4096 + wid * 512);
    }
    PHASE_BAR();
    __builtin_amdgcn_s_setprio(1);
#pragma unroll
    for (int m = 0; m < 4; ++m)
#pragma unroll
      for (int n = 0; n < 2; ++n)
#pragma unroll
        for (int ks = 0; ks < 2; ++ks)
          acc[4 + m][n] = __builtin_amdgcn_mfma_f32_16x16x32_bf16(a[m][ks], bg[n][ks], acc[4 + m][n], 0, 0, 0);
    __builtin_amdgcn_s_setprio(0);
    if (stB) { WAIT_VM(4); } else { WAIT_VM(0); }
    PHASE_BAR();
  };

  for (int t = 0; t < NK; t += 2) {
    iter(&sA[0][0], &sB[0][0], &sA[1][0], t);
    iter(&sA[1][0], &sB[1][0], &sA[0][0], t + 1);
  }

  __syncthreads();

  // epilogue: h = silu(g)*u
#pragma unroll
  for (int mm = 0; mm < 8; ++mm) {
#pragma unroll
    for (int np = 0; np < 2; ++np) {
      int col = jbase + wc * 32 + np * 16 + l15;
#pragma unroll
      for (int j = 0; j < 4; ++j) {
        int rl = wr * 128 + mm * 16 + lhi * 4 + j;
        int i = rowbase + rl;
        if (i < ne) {
          float g = acc[mm][np][j], u = acc[mm][np + 2][j];
          float hv = (g / (1.f + __expf(-g))) * u;
          hbuf[(size_t)(hb + i) * I_DIM + col] = __float2bfloat16(hv);
        }
      }
    }
  }
}

// ============================================================================
// GEMM2: y[slot] = coef * (h[slot] @ W2^T), compact bf16 ybuf. Same schedule.
// ============================================================================
__global__ __launch_bounds__(512, 2) void gemm2_kernel(
    const __hip_bfloat16* __restrict__ hbuf, const __hip_bfloat16* __restrict__ wb2,
    const int* __restrict__ cnt, const int* __restrict__ base,
    const float* __restrict__ wgt, __hip_bfloat16* __restrict__ ybuf)
{
  // XCD swizzle: 1536 blocks = 8 XCDs x 192 (24 row-blocks x 8 col-blocks)
  int lin = blockIdx.x;
  int swz = (lin & 7) * 192 + (lin >> 3);
  int e = swz / 192; int rem = swz - e * 192;
  int by = rem >> 3; int bx = rem & 7;
  const int ne = cnt[e];
  const int rowbase = by * 256;
  if (rowbase >= ne) return;
  const int nbase = bx * 256;
  const int hb = base[e];

  __shared__ short sA[2][256 * 64];
  __shared__ short sB[2][256 * 64];
  __shared__ float sW[256];

  const int tid = threadIdx.x, wid = tid >> 6, lane = tid & 63;
  const int wr = wid >> 2, wc = wid & 3;
  const int l15 = lane & 15, lhi = lane >> 4;
  const float* wgt_e = wgt + e * T_TOK;
  const char* hs = (const char*)hbuf;
  const char* w2s = (const char*)wb2 + (size_t)e * H_DIM * I_DIM * 2;

  if (tid < 256) {
    int i = rowbase + tid;
    sW[tid] = (i < ne) ? wgt_e[i] : 0.f;
  }

  const int cb = ((lane & 7) ^ (lane >> 3)) << 4;
  const char* aSrc[4]; const char* bSrc[4];
#pragma unroll
  for (int q = 0; q < 4; ++q) {
    int r = q * 64 + wid * 8 + (lane >> 3);
    int i = rowbase + r; if (i > ne - 1) i = ne - 1;
    aSrc[q] = hs + (size_t)(hb + i) * (I_DIM * 2) + cb;
    bSrc[q] = w2s + (size_t)(nbase + r) * (I_DIM * 2) + cb;
  }

  const int NK = I_DIM / 64;  // 22 (even)

#pragma unroll
  for (int q = 0; q < 4; ++q) async_copy16(bSrc[q], &sB[0][q * 4096 + wid * 512]);
#pragma unroll
  for (int q = 0; q < 4; ++q) async_copy16(aSrc[q], &sA[0][q * 4096 + wid * 512]);
#pragma unroll
  for (int q = 0; q < 4; ++q) async_copy16(bSrc[q] + 128, &sB[1][q * 4096 + wid * 512]);
#pragma unroll
  for (int q = 0; q < 4; ++q) async_copy16(aSrc[q] + 128, &sA[1][q * 4096 + wid * 512]);
  WAIT_VM(8);
  PHASE_BAR();

  f32x4 acc[8][4];
#pragma unroll
  for (int m = 0; m < 8; ++m)
#pragma unroll
    for (int n = 0; n < 4; ++n) acc[m][n] = (f32x4){0, 0, 0, 0};

  auto iter = [&](short* bufA, short* bufB, short* altA, int t) {
    const bool stA = (t >= 1) && (t + 1 < NK);
    const bool stB = (t + 2 < NK);
    const size_t kA = (size_t)(t + 1) * 128;
    const size_t kB = (size_t)(t + 2) * 128;
    bf16x8 a[4][2], b0[2][2], b1[2][2];

    // ph1
#pragma unroll
    for (int m = 0; m < 4; ++m)
#pragma unroll
      for (int ks = 0; ks < 2; ++ks)
        a[m][ks] = lds_read_swz(bufA, wr * 128 + m * 16 + l15, ks * 32 + (lhi << 3));
#pragma unroll
    for (int n = 0; n < 2; ++n)
#pragma unroll
      for (int ks = 0; ks < 2; ++ks)
        b0[n][ks] = lds_read_swz(bufB, wc * 64 + n * 16 + l15, ks * 32 + (lhi << 3));
    if (stA) {
      async_copy16(aSrc[0] + kA, altA + 0 * 4096 + wid * 512);
      async_copy16(aSrc[1] + kA, altA + 1 * 4096 + wid * 512);
    }
    PHASE_BAR();
    __builtin_amdgcn_s_setprio(1);
#pragma unroll
    for (int m = 0; m < 4; ++m)
#pragma unroll
      for (int n = 0; n < 2; ++n)
#pragma unroll
        for (int ks = 0; ks < 2; ++ks)
          acc[m][n] = __builtin_amdgcn_mfma_f32_16x16x32_bf16(a[m][ks], b0[n][ks], acc[m][n], 0, 0, 0);
    __builtin_amdgcn_s_setprio(0);
    PHASE_BAR();

    // ph2
#pragma unroll
    for (int n = 0; n < 2; ++n)
#pragma unroll
      for (int ks = 0; ks < 2; ++ks)
        b1[n][ks] = lds_read_swz(bufB, wc * 64 + 32 + n * 16 + l15, ks * 32 + (lhi << 3));
    if (stA) {
      async_copy16(aSrc[2] + kA, altA + 2 * 4096 + wid * 512);
      async_copy16(aSrc[3] + kA, altA + 3 * 4096 + wid * 512);
    }
    PHASE_BAR();
    __builtin_amdgcn_s_setprio(1);
#pragma unroll
    for (int m = 0; m < 4; ++m)
#pragma unroll
      for (int n = 0; n < 2; ++n)
#pragma unroll
        for (int ks = 0; ks < 2; ++ks)
          acc[m][2 + n] = __builtin_amdgcn_mfma_f32_16x16x32_bf16(a[m][ks], b1[n][ks], acc[m][2 + n], 0, 0, 0);
    __builtin_amdgcn_s_setprio(0);
    PHASE_BAR();

    // ph3
#pragma unroll
    for (int m = 0; m < 4; ++m)
#pragma unroll
      for (int ks = 0; ks < 2; ++ks)
        a[m][ks] = lds_read_swz(bufA, wr * 128 + 64 + m * 16 + l15, ks * 32 + (lhi << 3));
    if (stB) {
      async_copy16(bSrc[0] + kB, bufB + 0 * 4096 + wid * 512);
      async_copy16(bSrc[1] + kB, bufB + 1 * 4096 + wid * 512);
    }
    PHASE_BAR();
    __builtin_amdgcn_s_setprio(1);
#pragma unroll
    for (int m = 0; m < 4; ++m)
#pragma unroll
      for (int n = 0; n < 2; ++n)
#pragma unroll
        for (int ks = 0; ks < 2; ++ks)
          acc[4 + m][2 + n] = __builtin_amdgcn_mfma_f32_16x16x32_bf16(a[m][ks], b1[n][ks], acc[4 + m][2 + n], 0, 0, 0);
    __builtin_amdgcn_s_setprio(0);
    PHASE_BAR();

    // ph4
    if (stB) {
      async_copy16(bSrc[2] + kB, bufB + 2 * 4096 + wid * 512);
      async_copy16(bSrc[3] + kB, bufB + 3 * 4096 + wid * 512);
    }
    PHASE_BAR();
    __builtin_amdgcn_s_setprio(1);
#pragma unroll
    for (int m = 0; m < 4; ++m)
#pragma unroll
      for (int n = 0; n < 2; ++n)
#pragma unroll
        for (int ks = 0; ks < 2; ++ks)
          acc[4 + m][n] = __builtin_amdgcn_mfma_f32_16x16x32_bf16(a[m][ks], b0[n][ks], acc[4 + m][n], 0, 0, 0);
    __builtin_amdgcn_s_setprio(0);
    if (stB) { WAIT_VM(4); } else { WAIT_VM(0); }
    PHASE_BAR();
  };

  for (int t = 0; t < NK; t += 2) {
    iter(&sA[0][0], &sB[0][0], &sA[1][0], t);
    iter(&sA[1][0], &sB[1][0], &sA[0][0], t + 1);
  }

  __syncthreads();

#pragma unroll
  for (int mm = 0; mm < 8; ++mm) {
#pragma unroll
    for (int nn = 0; nn < 4; ++nn) {
      int col = nbase + wc * 64 + nn * 16 + l15;
#pragma unroll
      for (int j = 0; j < 4; ++j) {
        int rl = wr * 128 + mm * 16 + lhi * 4 + j;
        if (rowbase + rl < ne) {
          float y = acc[mm][nn][j] * sW[rl];
          ybuf[(size_t)(hb + rowbase + rl) * H_DIM + col] = __float2bfloat16(y);
        }
      }
    }
  }
}

// ---------------- combine: out[t] = y[slot1(t)] + y[slot2(t)] ----------------
__global__ __launch_bounds__(256) void combine_kernel(
    const __hip_bfloat16* __restrict__ ybuf, const int* __restrict__ base,
    const int* __restrict__ invE, const int* __restrict__ invP,
    float* __restrict__ out)
{
  int t = blockIdx.x;
  int s1 = base[invE[2 * t]] + invP[2 * t];
  int s2 = base[invE[2 * t + 1]] + invP[2 * t + 1];
  const ushort* y1 = (const ushort*)ybuf + (size_t)s1 * H_DIM;
  const ushort* y2 = (const ushort*)ybuf + (size_t)s2 * H_DIM;
  float* o = out + (size_t)t * H_DIM;
#pragma unroll
  for (int c0 = 0; c0 < H_DIM; c0 += 256 * 4) {
    int c = c0 + threadIdx.x * 4;
    ushort4 a = *(const ushort4*)(y1 + c);
    ushort4 b = *(const ushort4*)(y2 + c);
    float4 r;
    r.x = bfu2f(a.x) + bfu2f(b.x);
    r.y = bfu2f(a.y) + bfu2f(b.y);
    r.z = bfu2f(a.z) + bfu2f(b.z);
    r.w = bfu2f(a.w) + bfu2f(b.w);
    *(float4*)(o + c) = r;
  }
}

// ---------------- launch ----------------
extern "C" void kernel_launch(void* const* d_in, const int* in_sizes, int n_in,
                              void* d_out, int out_size, void* d_ws, size_t ws_size,
                              hipStream_t stream) {
  const float* x  = (const float*)d_in[0];
  const float* gw = (const float*)d_in[1];
  const float* w1 = (const float*)d_in[2];
  const float* w2 = (const float*)d_in[3];
  float* out = (float*)d_out;

  char* ws = (char*)d_ws;
  size_t o = 0;
  __hip_bfloat16* xb   = (__hip_bfloat16*)(ws + o); o += (size_t)T_TOK * H_DIM * 2;         // 33.5MB
  __hip_bfloat16* wb1  = (__hip_bfloat16*)(ws + o); o += (size_t)E_NUM * GU2 * H_DIM * 2;   // 92.3MB
  __hip_bfloat16* wb2  = (__hip_bfloat16*)(ws + o); o += (size_t)E_NUM * H_DIM * I_DIM * 2; // 46.1MB
  __hip_bfloat16* hbuf = (__hip_bfloat16*)(ws + o); o += (size_t)2 * T_TOK * I_DIM * 2;     // 46.1MB
  int*   idx  = (int*)(ws + o);   o += (size_t)E_NUM * T_TOK * 4;
  float* wgt  = (float*)(ws + o); o += (size_t)E_NUM * T_TOK * 4;
  int*   invE = (int*)(ws + o);   o += (size_t)2 * T_TOK * 4;
  int*   invP = (int*)(ws + o);   o += (size_t)2 * T_TOK * 4;
  int*   cnt  = (int*)(ws + o);   o += 64;
  int*   base = (int*)(ws + o);   o += 64;
  // ybuf (67.1MB bf16) aliases xb+wb1 (125.8MB): both dead once gemm1 completes.
  __hip_bfloat16* ybuf = (__hip_bfloat16*)ws;

  hipMemsetAsync(cnt, 0, 128, stream);  // cnt + base

  cvt_kernel<<<4096, 256, 0, stream>>>((const float4*)w1, (ushort4*)wb1, (E_NUM * GU2 * H_DIM) / 4);
  cvt_kernel<<<4096, 256, 0, stream>>>((const float4*)w2, (ushort4*)wb2, (E_NUM * H_DIM * I_DIM) / 4);

  gating_kernel<<<T_TOK / 4, 256, 0, stream>>>(x, gw, cnt, idx, wgt, invE, invP, xb);
  prefix_kernel<<<1, 64, 0, stream>>>(cnt, base);

  gemm1_kernel<<<dim3(2112), 512, 0, stream>>>(xb, wb1, cnt, base, idx, hbuf);
  gemm2_kernel<<<dim3(1536), 512, 0, stream>>>(hbuf, wb2, cnt, base, wgt, ybuf);

  combine_kernel<<<T_TOK, 256, 0, stream>>>(ybuf, base, invE, invP, out);
}

// Round 5
// 665.545 us; speedup vs baseline: 1.1463x; 1.0008x over previous
//
#include <hip/hip_runtime.h>
#include <hip/hip_bf16.h>
#include <stdint.h>

#define T_TOK 8192
#define H_DIM 2048
#define I_DIM 1408
#define E_NUM 8
#define GU2   2816   // 2*I

typedef __attribute__((ext_vector_type(8))) short bf16x8;
typedef __attribute__((ext_vector_type(4))) float f32x4;

__device__ __forceinline__ void async_copy16(const void* g, void* lds) {
  __builtin_amdgcn_global_load_lds(
      (const __attribute__((address_space(1))) uint32_t*)g,
      (__attribute__((address_space(3))) uint32_t*)lds, 16, 0, 0);
}

// CRITICAL: no "memory" clobber. An asm memory clobber makes the waitcnt
// legalizer insert s_waitcnt vmcnt(0) before the asm (it may "read" the LDS
// that in-flight global_load_lds writes), draining the pipeline at EVERY
// phase barrier. Builtin s_barrier has no memory effects -> loads stay in
// flight across barriers (m201/m218 pattern).
#define PHASE_BAR() __builtin_amdgcn_s_barrier()
#define WAIT_VM(n)  asm volatile("s_waitcnt vmcnt(" #n ")")

// Swizzled LDS read: tile is [256 rows][64 k] bf16, row stride 128B,
// byte ^= (row&7)<<4 spreads the 16-lane column read across all banks.
__device__ __forceinline__ bf16x8 lds_read_swz(const short* tile, int row, int kcol) {
  int byte = (row << 7) + (kcol << 1);
  byte ^= (row & 7) << 4;
  return *(const bf16x8*)((const char*)tile + byte);
}

__device__ __forceinline__ float bfu2f(unsigned short u) {
  union { unsigned int i; float f; } v; v.i = ((unsigned int)u) << 16; return v.f;
}

// ---------------- f32 -> bf16 conversion (weights) ----------------
__global__ __launch_bounds__(256) void cvt_kernel(const float4* __restrict__ in,
                                                  ushort4* __restrict__ out, int n4) {
  int i = blockIdx.x * blockDim.x + threadIdx.x;
  int stride = gridDim.x * blockDim.x;
  for (; i < n4; i += stride) {
    float4 v = in[i];
    ushort4 o;
    __hip_bfloat16 b;
    b = __float2bfloat16(v.x); o.x = *reinterpret_cast<unsigned short*>(&b);
    b = __float2bfloat16(v.y); o.y = *reinterpret_cast<unsigned short*>(&b);
    b = __float2bfloat16(v.z); o.z = *reinterpret_cast<unsigned short*>(&b);
    b = __float2bfloat16(v.w); o.w = *reinterpret_cast<unsigned short*>(&b);
    out[i] = o;
  }
}

// ---------- gating: logits -> top2 -> lists + inverse; also writes xb ----------
__global__ __launch_bounds__(256) void gating_kernel(
    const float* __restrict__ x, const float* __restrict__ gw,
    int* __restrict__ cnt, int* __restrict__ idx, float* __restrict__ wgt,
    int* __restrict__ invE, int* __restrict__ invP,
    __hip_bfloat16* __restrict__ xb) {
  int wave = threadIdx.x >> 6, lane = threadIdx.x & 63;
  int t = blockIdx.x * 4 + wave;
  if (t >= T_TOK) return;
  const float4* xr = (const float4*)(x + (size_t)t * H_DIM);
  ushort4* xo = (ushort4*)((unsigned short*)xb + (size_t)t * H_DIM);
  float acc[E_NUM];
#pragma unroll
  for (int e = 0; e < E_NUM; ++e) acc[e] = 0.f;
#pragma unroll
  for (int i = 0; i < H_DIM / 256; ++i) {   // 8 iters, float4 per lane
    int c = i * 64 + lane;
    float4 xv = xr[c];
    ushort4 o;
    __hip_bfloat16 b;
    b = __float2bfloat16(xv.x); o.x = *reinterpret_cast<unsigned short*>(&b);
    b = __float2bfloat16(xv.y); o.y = *reinterpret_cast<unsigned short*>(&b);
    b = __float2bfloat16(xv.z); o.z = *reinterpret_cast<unsigned short*>(&b);
    b = __float2bfloat16(xv.w); o.w = *reinterpret_cast<unsigned short*>(&b);
    xo[c] = o;
#pragma unroll
    for (int e = 0; e < E_NUM; ++e) {
      float4 g = ((const float4*)(gw + (size_t)e * H_DIM))[c];
      acc[e] += xv.x * g.x + xv.y * g.y + xv.z * g.z + xv.w * g.w;
    }
  }
#pragma unroll
  for (int e = 0; e < E_NUM; ++e) {
    float s = acc[e];
#pragma unroll
    for (int o = 32; o > 0; o >>= 1) s += __shfl_xor(s, o);
    acc[e] = s;
  }
  if (lane == 0) {
    int i1 = 0; float v1 = acc[0];
#pragma unroll
    for (int e = 1; e < E_NUM; ++e) if (acc[e] > v1) { v1 = acc[e]; i1 = e; }
    int i2 = -1; float v2 = -3.4e38f;
#pragma unroll
    for (int e = 0; e < E_NUM; ++e) if (e != i1 && acc[e] > v2) { v2 = acc[e]; i2 = e; }
    float p2 = expf(v2 - v1);
    float winv = 1.f / (1.f + p2);
    float w1 = winv, w2 = p2 * winv;
    int p = atomicAdd(&cnt[i1], 1);
    idx[i1 * T_TOK + p] = t; wgt[i1 * T_TOK + p] = w1;
    invE[2 * t] = i1; invP[2 * t] = p;
    p = atomicAdd(&cnt[i2], 1);
    idx[i2 * T_TOK + p] = t; wgt[i2 * T_TOK + p] = w2;
    invE[2 * t + 1] = i2; invP[2 * t + 1] = p;
  }
}

__global__ void prefix_kernel(const int* __restrict__ cnt, int* __restrict__ base) {
  if (threadIdx.x == 0 && blockIdx.x == 0) {
    int s = 0;
#pragma unroll
    for (int e = 0; e < E_NUM; ++e) { base[e] = s; s += cnt[e]; }
  }
}

// ============================================================================
// GEMM1: 256 slot-rows x 128 h-cols (256 B-rows interleaved g|u).
// 8-phase/2-K-tile schedule, counted vmcnt: A staged 1 tile ahead (ph1/2),
// B staged 2 tiles ahead into same-parity buffer (ph3/4). Boundary vmcnt(4)
// drains A/B(t+1), keeps B(t+2)'s 4 loads in flight across the barrier.
// ============================================================================
__global__ __launch_bounds__(512, 2) void gemm1_kernel(
    const __hip_bfloat16* __restrict__ xb, const __hip_bfloat16* __restrict__ wb1,
    const int* __restrict__ cnt, const int* __restrict__ base, const int* __restrict__ idx,
    __hip_bfloat16* __restrict__ hbuf)
{
  // XCD swizzle: 2112 blocks = 8 XCDs x 264 (24 row-blocks x 11 col-blocks)
  int lin = blockIdx.x;
  int swz = (lin & 7) * 264 + (lin >> 3);
  int e = swz / 264; int rem = swz - e * 264;
  int by = rem / 11; int bx = rem - by * 11;
  const int ne = cnt[e];
  const int rowbase = by * 256;
  if (rowbase >= ne) return;
  const int jbase = bx * 128;
  const int hb = base[e];

  __shared__ short sA[2][256 * 64];
  __shared__ short sB[2][256 * 64];

  const int tid = threadIdx.x, wid = tid >> 6, lane = tid & 63;
  const int wr = wid >> 2, wc = wid & 3;
  const int l15 = lane & 15, lhi = lane >> 4;
  const int* idx_e = idx + e * T_TOK;
  const char* xs = (const char*)xb;
  const char* w1s = (const char*)wb1 + (size_t)e * GU2 * H_DIM * 2;

  const int cb = ((lane & 7) ^ (lane >> 3)) << 4;  // pre-swizzled source col
  const char* aSrc[4]; const char* bSrc[4];
#pragma unroll
  for (int q = 0; q < 4; ++q) {
    int r = q * 64 + wid * 8 + (lane >> 3);
    int i = rowbase + r; if (i > ne - 1) i = ne - 1;
    aSrc[q] = xs + (size_t)idx_e[i] * (H_DIM * 2) + cb;
    int s = r & 63;
    int wrow = (s < 32) ? (jbase + q * 32 + s) : (I_DIM + jbase + q * 32 + (s - 32));
    bSrc[q] = w1s + (size_t)wrow * (H_DIM * 2) + cb;
  }

  const int NK = H_DIM / 64;  // 32 (even)

  // prologue: B(0), A(0), B(1), A(1); drain tile-0's 8, keep tile-1's 8
#pragma unroll
  for (int q = 0; q < 4; ++q) async_copy16(bSrc[q], &sB[0][q * 4096 + wid * 512]);
#pragma unroll
  for (int q = 0; q < 4; ++q) async_copy16(aSrc[q], &sA[0][q * 4096 + wid * 512]);
#pragma unroll
  for (int q = 0; q < 4; ++q) async_copy16(bSrc[q] + 128, &sB[1][q * 4096 + wid * 512]);
#pragma unroll
  for (int q = 0; q < 4; ++q) async_copy16(aSrc[q] + 128, &sA[1][q * 4096 + wid * 512]);
  WAIT_VM(8);
  PHASE_BAR();

  f32x4 acc[8][4];
#pragma unroll
  for (int m = 0; m < 8; ++m)
#pragma unroll
    for (int n = 0; n < 4; ++n) acc[m][n] = (f32x4){0, 0, 0, 0};

  auto iter = [&](short* bufA, short* bufB, short* altA, int t) {
    const bool stA = (t >= 1) && (t + 1 < NK);
    const bool stB = (t + 2 < NK);
    const size_t kA = (size_t)(t + 1) * 128;
    const size_t kB = (size_t)(t + 2) * 128;
    bf16x8 a[4][2], bg[2][2], bu[2][2];

    // ---- ph1: read a-lo quarter + bg; stage A-lo(t+1); MFMA Qg-lo ----
#pragma unroll
    for (int m = 0; m < 4; ++m)
#pragma unroll
      for (int ks = 0; ks < 2; ++ks)
        a[m][ks] = lds_read_swz(bufA, wr * 128 + m * 16 + l15, ks * 32 + (lhi << 3));
#pragma unroll
    for (int n = 0; n < 2; ++n)
#pragma unroll
      for (int ks = 0; ks < 2; ++ks)
        bg[n][ks] = lds_read_swz(bufB, wc * 64 + n * 16 + l15, ks * 32 + (lhi << 3));
    if (stA) {
      async_copy16(aSrc[0] + kA, altA + 0 * 4096 + wid * 512);
      async_copy16(aSrc[1] + kA, altA + 1 * 4096 + wid * 512);
    }
    PHASE_BAR();
    __builtin_amdgcn_s_setprio(1);
#pragma unroll
    for (int m = 0; m < 4; ++m)
#pragma unroll
      for (int n = 0; n < 2; ++n)
#pragma unroll
        for (int ks = 0; ks < 2; ++ks)
          acc[m][n] = __builtin_amdgcn_mfma_f32_16x16x32_bf16(a[m][ks], bg[n][ks], acc[m][n], 0, 0, 0);
    __builtin_amdgcn_s_setprio(0);
    PHASE_BAR();

    // ---- ph2: read bu; stage A-hi(t+1); MFMA Qu-lo ----
#pragma unroll
    for (int n = 0; n < 2; ++n)
#pragma unroll
      for (int ks = 0; ks < 2; ++ks)
        bu[n][ks] = lds_read_swz(bufB, wc * 64 + 32 + n * 16 + l15, ks * 32 + (lhi << 3));
    if (stA) {
      async_copy16(aSrc[2] + kA, altA + 2 * 4096 + wid * 512);
      async_copy16(aSrc[3] + kA, altA + 3 * 4096 + wid * 512);
    }
    PHASE_BAR();
    __builtin_amdgcn_s_setprio(1);
#pragma unroll
    for (int m = 0; m < 4; ++m)
#pragma unroll
      for (int n = 0; n < 2; ++n)
#pragma unroll
        for (int ks = 0; ks < 2; ++ks)
          acc[m][2 + n] = __builtin_amdgcn_mfma_f32_16x16x32_bf16(a[m][ks], bu[n][ks], acc[m][2 + n], 0, 0, 0);
    __builtin_amdgcn_s_setprio(0);
    PHASE_BAR();

    // ---- ph3: read a-hi quarter; stage B-lo(t+2) into bufB; MFMA Qu-hi ----
#pragma unroll
    for (int m = 0; m < 4; ++m)
#pragma unroll
      for (int ks = 0; ks < 2; ++ks)
        a[m][ks] = lds_read_swz(bufA, wr * 128 + 64 + m * 16 + l15, ks * 32 + (lhi << 3));
    if (stB) {
      async_copy16(bSrc[0] + kB, bufB + 0 * 4096 + wid * 512);
      async_copy16(bSrc[1] + kB, bufB + 1 * 4096 + wid * 512);
    }
    PHASE_BAR();
    __builtin_amdgcn_s_setprio(1);
#pragma unroll
    for (int m = 0; m < 4; ++m)
#pragma unroll
      for (int n = 0; n < 2; ++n)
#pragma unroll
        for (int ks = 0; ks < 2; ++ks)
          acc[4 + m][2 + n] = __builtin_amdgcn_mfma_f32_16x16x32_bf16(a[m][ks], bu[n][ks], acc[4 + m][2 + n], 0, 0, 0);
    __builtin_amdgcn_s_setprio(0);
    PHASE_BAR();

    // ---- ph4: stage B-hi(t+2); MFMA Qg-hi; boundary vmcnt(4) ----
    if (stB) {
      async_copy16(bSrc[2] + kB, bufB + 2 * 4096 + wid * 512);
      async_copy16(bSrc[3] + kB, bufB + 3 * 4096 + wid * 512);
    }
    PHASE_BAR();
    __builtin_amdgcn_s_setprio(1);
#pragma unroll
    for (int m = 0; m < 4; ++m)
#pragma unroll
      for (int n = 0; n < 2; ++n)
#pragma unroll
        for (int ks = 0; ks < 2; ++ks)
          acc[4 + m][n] = __builtin_amdgcn_mfma_f32_16x16x32_bf16(a[m][ks], bg[n][ks], acc[4 + m][n], 0, 0, 0);
    __builtin_amdgcn_s_setprio(0);
    if (stB) { WAIT_VM(4); } else { WAIT_VM(0); }
    PHASE_BAR();
  };

  for (int t = 0; t < NK; t += 2) {
    iter(&sA[0][0], &sB[0][0], &sA[1][0], t);
    iter(&sA[1][0], &sB[1][0], &sA[0][0], t + 1);
  }

  __syncthreads();

  // epilogue: h = silu(g)*u
#pragma unroll
  for (int mm = 0; mm < 8; ++mm) {
#pragma unroll
    for (int np = 0; np < 2; ++np) {
      int col = jbase + wc * 32 + np * 16 + l15;
#pragma unroll
      for (int j = 0; j < 4; ++j) {
        int rl = wr * 128 + mm * 16 + lhi * 4 + j;
        int i = rowbase + rl;
        if (i < ne) {
          float g = acc[mm][np][j], u = acc[mm][np + 2][j];
          float hv = (g / (1.f + __expf(-g))) * u;
          hbuf[(size_t)(hb + i) * I_DIM + col] = __float2bfloat16(hv);
        }
      }
    }
  }
}

// ============================================================================
// GEMM2: y[slot] = coef * (h[slot] @ W2^T), compact bf16 ybuf. Same schedule.
// ============================================================================
__global__ __launch_bounds__(512, 2) void gemm2_kernel(
    const __hip_bfloat16* __restrict__ hbuf, const __hip_bfloat16* __restrict__ wb2,
    const int* __restrict__ cnt, const int* __restrict__ base,
    const float* __restrict__ wgt, __hip_bfloat16* __restrict__ ybuf)
{
  // XCD swizzle: 1536 blocks = 8 XCDs x 192 (24 row-blocks x 8 col-blocks)
  int lin = blockIdx.x;
  int swz = (lin & 7) * 192 + (lin >> 3);
  int e = swz / 192; int rem = swz - e * 192;
  int by = rem >> 3; int bx = rem & 7;
  const int ne = cnt[e];
  const int rowbase = by * 256;
  if (rowbase >= ne) return;
  const int nbase = bx * 256;
  const int hb = base[e];

  __shared__ short sA[2][256 * 64];
  __shared__ short sB[2][256 * 64];
  __shared__ float sW[256];

  const int tid = threadIdx.x, wid = tid >> 6, lane = tid & 63;
  const int wr = wid >> 2, wc = wid & 3;
  const int l15 = lane & 15, lhi = lane >> 4;
  const float* wgt_e = wgt + e * T_TOK;
  const char* hs = (const char*)hbuf;
  const char* w2s = (const char*)wb2 + (size_t)e * H_DIM * I_DIM * 2;

  if (tid < 256) {
    int i = rowbase + tid;
    sW[tid] = (i < ne) ? wgt_e[i] : 0.f;
  }

  const int cb = ((lane & 7) ^ (lane >> 3)) << 4;
  const char* aSrc[4]; const char* bSrc[4];
#pragma unroll
  for (int q = 0; q < 4; ++q) {
    int r = q * 64 + wid * 8 + (lane >> 3);
    int i = rowbase + r; if (i > ne - 1) i = ne - 1;
    aSrc[q] = hs + (size_t)(hb + i) * (I_DIM * 2) + cb;
    bSrc[q] = w2s + (size_t)(nbase + r) * (I_DIM * 2) + cb;
  }

  const int NK = I_DIM / 64;  // 22 (even)

#pragma unroll
  for (int q = 0; q < 4; ++q) async_copy16(bSrc[q], &sB[0][q * 4096 + wid * 512]);
#pragma unroll
  for (int q = 0; q < 4; ++q) async_copy16(aSrc[q], &sA[0][q * 4096 + wid * 512]);
#pragma unroll
  for (int q = 0; q < 4; ++q) async_copy16(bSrc[q] + 128, &sB[1][q * 4096 + wid * 512]);
#pragma unroll
  for (int q = 0; q < 4; ++q) async_copy16(aSrc[q] + 128, &sA[1][q * 4096 + wid * 512]);
  WAIT_VM(8);
  PHASE_BAR();

  f32x4 acc[8][4];
#pragma unroll
  for (int m = 0; m < 8; ++m)
#pragma unroll
    for (int n = 0; n < 4; ++n) acc[m][n] = (f32x4){0, 0, 0, 0};

  auto iter = [&](short* bufA, short* bufB, short* altA, int t) {
    const bool stA = (t >= 1) && (t + 1 < NK);
    const bool stB = (t + 2 < NK);
    const size_t kA = (size_t)(t + 1) * 128;
    const size_t kB = (size_t)(t + 2) * 128;
    bf16x8 a[4][2], b0[2][2], b1[2][2];

    // ph1
#pragma unroll
    for (int m = 0; m < 4; ++m)
#pragma unroll
      for (int ks = 0; ks < 2; ++ks)
        a[m][ks] = lds_read_swz(bufA, wr * 128 + m * 16 + l15, ks * 32 + (lhi << 3));
#pragma unroll
    for (int n = 0; n < 2; ++n)
#pragma unroll
      for (int ks = 0; ks < 2; ++ks)
        b0[n][ks] = lds_read_swz(bufB, wc * 64 + n * 16 + l15, ks * 32 + (lhi << 3));
    if (stA) {
      async_copy16(aSrc[0] + kA, altA + 0 * 4096 + wid * 512);
      async_copy16(aSrc[1] + kA, altA + 1 * 4096 + wid * 512);
    }
    PHASE_BAR();
    __builtin_amdgcn_s_setprio(1);
#pragma unroll
    for (int m = 0; m < 4; ++m)
#pragma unroll
      for (int n = 0; n < 2; ++n)
#pragma unroll
        for (int ks = 0; ks < 2; ++ks)
          acc[m][n] = __builtin_amdgcn_mfma_f32_16x16x32_bf16(a[m][ks], b0[n][ks], acc[m][n], 0, 0, 0);
    __builtin_amdgcn_s_setprio(0);
    PHASE_BAR();

    // ph2
#pragma unroll
    for (int n = 0; n < 2; ++n)
#pragma unroll
      for (int ks = 0; ks < 2; ++ks)
        b1[n][ks] = lds_read_swz(bufB, wc * 64 + 32 + n * 16 + l15, ks * 32 + (lhi << 3));
    if (stA) {
      async_copy16(aSrc[2] + kA, altA + 2 * 4096 + wid * 512);
      async_copy16(aSrc[3] + kA, altA + 3 * 4096 + wid * 512);
    }
    PHASE_BAR();
    __builtin_amdgcn_s_setprio(1);
#pragma unroll
    for (int m = 0; m < 4; ++m)
#pragma unroll
      for (int n = 0; n < 2; ++n)
#pragma unroll
        for (int ks = 0; ks < 2; ++ks)
          acc[m][2 + n] = __builtin_amdgcn_mfma_f32_16x16x32_bf16(a[m][ks], b1[n][ks], acc[m][2 + n], 0, 0, 0);
    __builtin_amdgcn_s_setprio(0);
    PHASE_BAR();

    // ph3
#pragma unroll
    for (int m = 0; m < 4; ++m)
#pragma unroll
      for (int ks = 0; ks < 2; ++ks)
        a[m][ks] = lds_read_swz(bufA, wr * 128 + 64 + m * 16 + l15, ks * 32 + (lhi << 3));
    if (stB) {
      async_copy16(bSrc[0] + kB, bufB + 0 * 4096 + wid * 512);
      async_copy16(bSrc[1] + kB, bufB + 1 * 4096 + wid * 512);
    }
    PHASE_BAR();
    __builtin_amdgcn_s_setprio(1);
#pragma unroll
    for (int m = 0; m < 4; ++m)
#pragma unroll
      for (int n = 0; n < 2; ++n)
#pragma unroll
        for (int ks = 0; ks < 2; ++ks)
          acc[4 + m][2 + n] = __builtin_amdgcn_mfma_f32_16x16x32_bf16(a[m][ks], b1[n][ks], acc[4 + m][2 + n], 0, 0, 0);
    __builtin_amdgcn_s_setprio(0);
    PHASE_BAR();

    // ph4
    if (stB) {
      async_copy16(bSrc[2] + kB, bufB + 2 * 4096 + wid * 512);
      async_copy16(bSrc[3] + kB, bufB + 3 * 4096 + wid * 512);
    }
    PHASE_BAR();
    __builtin_amdgcn_s_setprio(1);
#pragma unroll
    for (int m = 0; m < 4; ++m)
#pragma unroll
      for (int n = 0; n < 2; ++n)
#pragma unroll
        for (int ks = 0; ks < 2; ++ks)
          acc[4 + m][n] = __builtin_amdgcn_mfma_f32_16x16x32_bf16(a[m][ks], b0[n][ks], acc[4 + m][n], 0, 0, 0);
    __builtin_amdgcn_s_setprio(0);
    if (stB) { WAIT_VM(4); } else { WAIT_VM(0); }
    PHASE_BAR();
  };

  for (int t = 0; t < NK; t += 2) {
    iter(&sA[0][0], &sB[0][0], &sA[1][0], t);
    iter(&sA[1][0], &sB[1][0], &sA[0][0], t + 1);
  }

  __syncthreads();

#pragma unroll
  for (int mm = 0; mm < 8; ++mm) {
#pragma unroll
    for (int nn = 0; nn < 4; ++nn) {
      int col = nbase + wc * 64 + nn * 16 + l15;
#pragma unroll
      for (int j = 0; j < 4; ++j) {
        int rl = wr * 128 + mm * 16 + lhi * 4 + j;
        if (rowbase + rl < ne) {
          float y = acc[mm][nn][j] * sW[rl];
          ybuf[(size_t)(hb + rowbase + rl) * H_DIM + col] = __float2bfloat16(y);
        }
      }
    }
  }
}

// ---------------- combine: out[t] = y[slot1(t)] + y[slot2(t)] ----------------
__global__ __launch_bounds__(256) void combine_kernel(
    const __hip_bfloat16* __restrict__ ybuf, const int* __restrict__ base,
    const int* __restrict__ invE, const int* __restrict__ invP,
    float* __restrict__ out)
{
  int t = blockIdx.x;
  int s1 = base[invE[2 * t]] + invP[2 * t];
  int s2 = base[invE[2 * t + 1]] + invP[2 * t + 1];
  const ushort* y1 = (const ushort*)ybuf + (size_t)s1 * H_DIM;
  const ushort* y2 = (const ushort*)ybuf + (size_t)s2 * H_DIM;
  float* o = out + (size_t)t * H_DIM;
#pragma unroll
  for (int c0 = 0; c0 < H_DIM; c0 += 256 * 4) {
    int c = c0 + threadIdx.x * 4;
    ushort4 a = *(const ushort4*)(y1 + c);
    ushort4 b = *(const ushort4*)(y2 + c);
    float4 r;
    r.x = bfu2f(a.x) + bfu2f(b.x);
    r.y = bfu2f(a.y) + bfu2f(b.y);
    r.z = bfu2f(a.z) + bfu2f(b.z);
    r.w = bfu2f(a.w) + bfu2f(b.w);
    *(float4*)(o + c) = r;
  }
}

// ---------------- launch ----------------
extern "C" void kernel_launch(void* const* d_in, const int* in_sizes, int n_in,
                              void* d_out, int out_size, void* d_ws, size_t ws_size,
                              hipStream_t stream) {
  const float* x  = (const float*)d_in[0];
  const float* gw = (const float*)d_in[1];
  const float* w1 = (const float*)d_in[2];
  const float* w2 = (const float*)d_in[3];
  float* out = (float*)d_out;

  char* ws = (char*)d_ws;
  size_t o = 0;
  __hip_bfloat16* xb   = (__hip_bfloat16*)(ws + o); o += (size_t)T_TOK * H_DIM * 2;         // 33.5MB
  __hip_bfloat16* wb1  = (__hip_bfloat16*)(ws + o); o += (size_t)E_NUM * GU2 * H_DIM * 2;   // 92.3MB
  __hip_bfloat16* wb2  = (__hip_bfloat16*)(ws + o); o += (size_t)E_NUM * H_DIM * I_DIM * 2; // 46.1MB
  __hip_bfloat16* hbuf = (__hip_bfloat16*)(ws + o); o += (size_t)2 * T_TOK * I_DIM * 2;     // 46.1MB
  int*   idx  = (int*)(ws + o);   o += (size_t)E_NUM * T_TOK * 4;
  float* wgt  = (float*)(ws + o); o += (size_t)E_NUM * T_TOK * 4;
  int*   invE = (int*)(ws + o);   o += (size_t)2 * T_TOK * 4;
  int*   invP = (int*)(ws + o);   o += (size_t)2 * T_TOK * 4;
  int*   cnt  = (int*)(ws + o);   o += 64;
  int*   base = (int*)(ws + o);   o += 64;
  // ybuf (67.1MB bf16) aliases xb+wb1 (125.8MB): both dead once gemm1 completes.
  __hip_bfloat16* ybuf = (__hip_bfloat16*)ws;

  hipMemsetAsync(cnt, 0, 128, stream);  // cnt + base

  cvt_kernel<<<4096, 256, 0, stream>>>((const float4*)w1, (ushort4*)wb1, (E_NUM * GU2 * H_DIM) / 4);
  cvt_kernel<<<4096, 256, 0, stream>>>((const float4*)w2, (ushort4*)wb2, (E_NUM * H_DIM * I_DIM) / 4);

  gating_kernel<<<T_TOK / 4, 256, 0, stream>>>(x, gw, cnt, idx, wgt, invE, invP, xb);
  prefix_kernel<<<1, 64, 0, stream>>>(cnt, base);

  gemm1_kernel<<<dim3(2112), 512, 0, stream>>>(xb, wb1, cnt, base, idx, hbuf);
  gemm2_kernel<<<dim3(1536), 512, 0, stream>>>(hbuf, wb2, cnt, base, wgt, ybuf);

  combine_kernel<<<T_TOK, 256, 0, stream>>>(ybuf, base, invE, invP, out);
}